// Round 1
// baseline (478.027 us; speedup 1.0000x reference)
//
#include <hip/hip_runtime.h>

#define NEG_SLOPE 0.1f

__device__ __forceinline__ float leaky(float v) { return v > 0.0f ? v : NEG_SLOPE * v; }

// ---------------------------------------------------------------------------
// K1: C[M,64] = A[M,K] @ B[K,64] + bias        (M=4096, K=1024, N=64), no act
// BM=32, BN=64, BK=32, 256 threads, 2x4 micro-tile
// ---------------------------------------------------------------------------
__global__ __launch_bounds__(256) void gemm_n64(const float* __restrict__ A,
                                                const float* __restrict__ B,
                                                const float* __restrict__ bias,
                                                float* __restrict__ C, int K)
{
    __shared__ alignas(16) float As[32][33];   // [k][m], padded
    __shared__ alignas(16) float Bs[32][64];
    const int tid  = threadIdx.x;
    const int row0 = blockIdx.y * 32;
    const int r0   = (tid >> 4) * 2;
    const int c0   = (tid & 15) * 4;
    const int am   = tid >> 3;
    const int ak   = (tid & 7) * 4;
    float acc[2][4] = {};

    for (int k0 = 0; k0 < K; k0 += 32) {
        float4 va = *reinterpret_cast<const float4*>(&A[(size_t)(row0 + am) * K + k0 + ak]);
        As[ak + 0][am] = va.x; As[ak + 1][am] = va.y;
        As[ak + 2][am] = va.z; As[ak + 3][am] = va.w;
#pragma unroll
        for (int p = 0; p < 2; ++p) {
            int idx = tid + p * 256;
            int kk  = idx >> 4;
            int nq  = (idx & 15) * 4;
            *reinterpret_cast<float4*>(&Bs[kk][nq]) =
                *reinterpret_cast<const float4*>(&B[(size_t)(k0 + kk) * 64 + nq]);
        }
        __syncthreads();
#pragma unroll
        for (int k = 0; k < 32; ++k) {
            float a0 = As[k][r0], a1 = As[k][r0 + 1];
            float4 bv = *reinterpret_cast<const float4*>(&Bs[k][c0]);
            acc[0][0] = fmaf(a0, bv.x, acc[0][0]); acc[0][1] = fmaf(a0, bv.y, acc[0][1]);
            acc[0][2] = fmaf(a0, bv.z, acc[0][2]); acc[0][3] = fmaf(a0, bv.w, acc[0][3]);
            acc[1][0] = fmaf(a1, bv.x, acc[1][0]); acc[1][1] = fmaf(a1, bv.y, acc[1][1]);
            acc[1][2] = fmaf(a1, bv.z, acc[1][2]); acc[1][3] = fmaf(a1, bv.w, acc[1][3]);
        }
        __syncthreads();
    }
#pragma unroll
    for (int i = 0; i < 2; ++i) {
        float4 o;
        o.x = acc[i][0] + bias[c0 + 0];
        o.y = acc[i][1] + bias[c0 + 1];
        o.z = acc[i][2] + bias[c0 + 2];
        o.w = acc[i][3] + bias[c0 + 3];
        *reinterpret_cast<float4*>(&C[(size_t)(row0 + r0 + i) * 64 + c0]) = o;
    }
}

// ---------------------------------------------------------------------------
// K2/K3: C[M,1024] = act(A[M,K] @ B[K,1024] + bias)   (M=4096)
// BM=BN=128, BK=32, 256 threads, 8x8 micro-tile (2x2 blocks of 4x4),
// register prefetch of next K-tile.
// ---------------------------------------------------------------------------
template <bool ACT>
__global__ __launch_bounds__(256) void gemm_n1024(const float* __restrict__ A,
                                                  const float* __restrict__ B,
                                                  const float* __restrict__ bias,
                                                  float* __restrict__ C, int K)
{
    __shared__ alignas(16) float As[32][132];  // [k][m], padded (132*4=528B rows, 16B aligned)
    __shared__ alignas(16) float Bs[32][128];
    const int tid  = threadIdx.x;
    const int row0 = blockIdx.y * 128;
    const int col0 = blockIdx.x * 128;
    const int tm0  = (tid >> 4) * 4;
    const int tn0  = (tid & 15) * 4;
    float acc[2][2][4][4] = {};
    float4 pa[4], pb[4];

    auto load_regs = [&](int k0) {
#pragma unroll
        for (int p = 0; p < 4; ++p) {
            int idx = tid + p * 256;
            int m   = idx >> 3;
            int kq  = (idx & 7) * 4;
            pa[p] = *reinterpret_cast<const float4*>(&A[(size_t)(row0 + m) * K + k0 + kq]);
            int kk = idx >> 5;
            int nq = (idx & 31) * 4;
            pb[p] = *reinterpret_cast<const float4*>(&B[(size_t)(k0 + kk) * 1024 + col0 + nq]);
        }
    };

    load_regs(0);
    for (int k0 = 0; k0 < K; k0 += 32) {
#pragma unroll
        for (int p = 0; p < 4; ++p) {
            int idx = tid + p * 256;
            int m   = idx >> 3;
            int kq  = (idx & 7) * 4;
            As[kq + 0][m] = pa[p].x; As[kq + 1][m] = pa[p].y;
            As[kq + 2][m] = pa[p].z; As[kq + 3][m] = pa[p].w;
            int kk = idx >> 5;
            int nq = (idx & 31) * 4;
            *reinterpret_cast<float4*>(&Bs[kk][nq]) = pb[p];
        }
        __syncthreads();
        if (k0 + 32 < K) load_regs(k0 + 32);   // overlap next-tile loads with compute
#pragma unroll
        for (int k = 0; k < 32; ++k) {
            float a[2][4], b[2][4];
            *reinterpret_cast<float4*>(a[0]) = *reinterpret_cast<const float4*>(&As[k][tm0]);
            *reinterpret_cast<float4*>(a[1]) = *reinterpret_cast<const float4*>(&As[k][64 + tm0]);
            *reinterpret_cast<float4*>(b[0]) = *reinterpret_cast<const float4*>(&Bs[k][tn0]);
            *reinterpret_cast<float4*>(b[1]) = *reinterpret_cast<const float4*>(&Bs[k][64 + tn0]);
#pragma unroll
            for (int bi = 0; bi < 2; ++bi)
#pragma unroll
                for (int bj = 0; bj < 2; ++bj)
#pragma unroll
                    for (int i = 0; i < 4; ++i)
#pragma unroll
                        for (int j = 0; j < 4; ++j)
                            acc[bi][bj][i][j] = fmaf(a[bi][i], b[bj][j], acc[bi][bj][i][j]);
        }
        __syncthreads();
    }
#pragma unroll
    for (int bi = 0; bi < 2; ++bi)
#pragma unroll
        for (int i = 0; i < 4; ++i) {
            int rr = row0 + bi * 64 + tm0 + i;
#pragma unroll
            for (int bj = 0; bj < 2; ++bj) {
                int cc = col0 + bj * 64 + tn0;
                float4 o;
                o.x = acc[bi][bj][i][0] + bias[cc + 0];
                o.y = acc[bi][bj][i][1] + bias[cc + 1];
                o.z = acc[bi][bj][i][2] + bias[cc + 2];
                o.w = acc[bi][bj][i][3] + bias[cc + 3];
                if (ACT) { o.x = leaky(o.x); o.y = leaky(o.y); o.z = leaky(o.z); o.w = leaky(o.w); }
                *reinterpret_cast<float4*>(&C[(size_t)rr * 1024 + cc]) = o;
            }
        }
}

// ---------------------------------------------------------------------------
// K4: fused AdditiveLayer1 -> AdditiveLayer2 -> PCA2 -> last
// Streams over r=0..63; never materializes a / a2 in global memory.
// BM=16 rows per WG, 256 threads, grid = 256 WGs. t2 kept in registers.
// ---------------------------------------------------------------------------
__global__ __launch_bounds__(256) void fused_tail(const float* __restrict__ h2,
    const float* __restrict__ a1W, const float* __restrict__ a1b, const float* __restrict__ a1bias,
    const float* __restrict__ a2W, const float* __restrict__ a2b, const float* __restrict__ a2bias,
    const float* __restrict__ Wp2, const float* __restrict__ bp2,
    const float* __restrict__ Wl,  const float* __restrict__ bl,
    float* __restrict__ out)
{
    __shared__ alignas(16) float hs[16 * 16];    // h2 slice [16 rows][16 k]
    __shared__ alignas(16) float w1s[16 * 64];   // add1_W[r]
    __shared__ alignas(16) float w2s[64 * 64];   // add2_W[r]
    __shared__ alignas(16) float wps[64 * 64];   // W_pca2[r*64 .. r*64+63][:]
    __shared__ alignas(16) float as_[16 * 68];   // a_r, padded stride 68
    __shared__ alignas(16) float a2s[16 * 68];   // a2_r

    const int tid  = threadIdx.x;
    const int row0 = blockIdx.x * 16;
    const int row  = tid >> 4;     // 0..15
    const int cl   = tid & 15;
    const int c4   = cl * 4;
    const float bias1 = a1bias[0], bias2 = a2bias[0];

    float4 ph, pw1, pw2[4], pwp[4];
    auto load_stage = [&](int r) {
        if (tid < 64)
            ph = *reinterpret_cast<const float4*>(
                &h2[(size_t)(row0 + (tid >> 2)) * 1024 + r * 16 + (tid & 3) * 4]);
        pw1 = *reinterpret_cast<const float4*>(&a1W[(size_t)r * 1024 + tid * 4]);
#pragma unroll
        for (int p = 0; p < 4; ++p) {
            pw2[p] = *reinterpret_cast<const float4*>(&a2W[(size_t)r * 4096 + (tid + p * 256) * 4]);
            pwp[p] = *reinterpret_cast<const float4*>(&Wp2[(size_t)r * 4096 + (tid + p * 256) * 4]);
        }
    };

    load_stage(0);
    float t2a[4] = {0.f, 0.f, 0.f, 0.f};

    for (int r = 0; r < 64; ++r) {
        // ---- store staged weights/activations to LDS
        if (tid < 64) *reinterpret_cast<float4*>(&hs[tid * 4]) = ph;
        *reinterpret_cast<float4*>(&w1s[tid * 4]) = pw1;
#pragma unroll
        for (int p = 0; p < 4; ++p) {
            *reinterpret_cast<float4*>(&w2s[(tid + p * 256) * 4]) = pw2[p];
            *reinterpret_cast<float4*>(&wps[(tid + p * 256) * 4]) = pwp[p];
        }
        __syncthreads();

        // ---- phase A: a_r[16,64] = leaky(hslice @ add1_W[r] + add1_b[r] + bias1)
        float acc[4] = {0.f, 0.f, 0.f, 0.f};
#pragma unroll
        for (int k = 0; k < 16; ++k) {
            float hv  = hs[row * 16 + k];
            float4 w  = *reinterpret_cast<const float4*>(&w1s[k * 64 + c4]);
            acc[0] = fmaf(hv, w.x, acc[0]); acc[1] = fmaf(hv, w.y, acc[1]);
            acc[2] = fmaf(hv, w.z, acc[2]); acc[3] = fmaf(hv, w.w, acc[3]);
        }
        {
            float4 ab = *reinterpret_cast<const float4*>(&a1b[r * 64 + c4]);
            float4 av;
            av.x = leaky(acc[0] + ab.x + bias1);
            av.y = leaky(acc[1] + ab.y + bias1);
            av.z = leaky(acc[2] + ab.z + bias1);
            av.w = leaky(acc[3] + ab.w + bias1);
            *reinterpret_cast<float4*>(&as_[row * 68 + c4]) = av;
        }
        __syncthreads();

        if (r < 63) load_stage(r + 1);  // prefetch next r's weights during phase B/C

        // ---- phase B: a2_r[16,64] = leaky(a_r @ add2_W[r] + add2_b[r] + bias2)
        acc[0] = acc[1] = acc[2] = acc[3] = 0.f;
#pragma unroll
        for (int i = 0; i < 64; ++i) {
            float av  = as_[row * 68 + i];
            float4 w  = *reinterpret_cast<const float4*>(&w2s[i * 64 + c4]);
            acc[0] = fmaf(av, w.x, acc[0]); acc[1] = fmaf(av, w.y, acc[1]);
            acc[2] = fmaf(av, w.z, acc[2]); acc[3] = fmaf(av, w.w, acc[3]);
        }
        {
            float4 ab = *reinterpret_cast<const float4*>(&a2b[r * 64 + c4]);
            float4 av;
            av.x = leaky(acc[0] + ab.x + bias2);
            av.y = leaky(acc[1] + ab.y + bias2);
            av.z = leaky(acc[2] + ab.z + bias2);
            av.w = leaky(acc[3] + ab.w + bias2);
            *reinterpret_cast<float4*>(&a2s[row * 68 + c4]) = av;
        }
        __syncthreads();

        // ---- phase C: t2 += a2_r @ W_pca2[r*64:(r+1)*64, :]
#pragma unroll
        for (int i = 0; i < 64; ++i) {
            float av  = a2s[row * 68 + i];
            float4 w  = *reinterpret_cast<const float4*>(&wps[i * 64 + c4]);
            t2a[0] = fmaf(av, w.x, t2a[0]); t2a[1] = fmaf(av, w.y, t2a[1]);
            t2a[2] = fmaf(av, w.z, t2a[2]); t2a[3] = fmaf(av, w.w, t2a[3]);
        }
        __syncthreads();   // before next iteration's LDS stores
    }

    // ---- epilogue: out[row] = sum_n (t2[n]+bp2[n]) * Wl[n] + bl
    float4 bp = *reinterpret_cast<const float4*>(&bp2[c4]);
    float4 wl = *reinterpret_cast<const float4*>(&Wl[c4]);
    float part = (t2a[0] + bp.x) * wl.x + (t2a[1] + bp.y) * wl.y +
                 (t2a[2] + bp.z) * wl.z + (t2a[3] + bp.w) * wl.w;
    part += __shfl_xor(part, 1);
    part += __shfl_xor(part, 2);
    part += __shfl_xor(part, 4);
    part += __shfl_xor(part, 8);
    if (cl == 0) out[row0 + row] = part + bl[0];
}

// ---------------------------------------------------------------------------
extern "C" void kernel_launch(void* const* d_in, const int* in_sizes, int n_in,
                              void* d_out, int out_size, void* d_ws, size_t ws_size,
                              hipStream_t stream)
{
    const float* x      = (const float*)d_in[0];
    const float* Wpca   = (const float*)d_in[1];
    const float* bpca   = (const float*)d_in[2];
    const float* W1     = (const float*)d_in[3];
    const float* b1     = (const float*)d_in[4];
    const float* W2     = (const float*)d_in[5];
    const float* b2     = (const float*)d_in[6];
    const float* a1W    = (const float*)d_in[7];
    const float* a1b    = (const float*)d_in[8];
    const float* a1bias = (const float*)d_in[9];
    const float* a2W    = (const float*)d_in[10];
    const float* a2b    = (const float*)d_in[11];
    const float* a2bias = (const float*)d_in[12];
    const float* Wp2    = (const float*)d_in[13];
    const float* bp2    = (const float*)d_in[14];
    const float* Wl     = (const float*)d_in[15];
    const float* bl     = (const float*)d_in[16];
    float* out = (float*)d_out;

    float* t  = (float*)d_ws;            // 4096*64
    float* h1 = t  + (size_t)4096 * 64;  // 4096*1024
    float* h2 = h1 + (size_t)4096 * 1024;

    // t = x @ W_pca + b_pca
    gemm_n64<<<dim3(1, 128), 256, 0, stream>>>(x, Wpca, bpca, t, 1024);
    // h1 = leaky(t @ W1 + b1)
    gemm_n1024<true><<<dim3(8, 32), 256, 0, stream>>>(t, W1, b1, h1, 64);
    // h2 = leaky(h1 @ W2 + b2)
    gemm_n1024<true><<<dim3(8, 32), 256, 0, stream>>>(h1, W2, b2, h2, 1024);
    // fused additive chain + PCA2 + last
    fused_tail<<<dim3(256), 256, 0, stream>>>(h2, a1W, a1b, a1bias, a2W, a2b, a2bias,
                                              Wp2, bp2, Wl, bl, out);
}

// Round 2
// 288.222 us; speedup vs baseline: 1.6585x; 1.6585x over previous
//
#include <hip/hip_runtime.h>

#define NEG_SLOPE 0.1f

__device__ __forceinline__ float leaky(float v) { return v > 0.0f ? v : NEG_SLOPE * v; }

// ---------------------------------------------------------------------------
// K1: C[M,64] = A[M,K] @ B[K,64] + bias        (M=4096, K=1024, N=64), no act
// ---------------------------------------------------------------------------
__global__ __launch_bounds__(256) void gemm_n64(const float* __restrict__ A,
                                                const float* __restrict__ B,
                                                const float* __restrict__ bias,
                                                float* __restrict__ C, int K)
{
    __shared__ alignas(16) float As[32][33];   // [k][m], padded
    __shared__ alignas(16) float Bs[32][64];
    const int tid  = threadIdx.x;
    const int row0 = blockIdx.y * 32;
    const int r0   = (tid >> 4) * 2;
    const int c0   = (tid & 15) * 4;
    const int am   = tid >> 3;
    const int ak   = (tid & 7) * 4;
    float acc[2][4] = {};

    for (int k0 = 0; k0 < K; k0 += 32) {
        float4 va = *reinterpret_cast<const float4*>(&A[(size_t)(row0 + am) * K + k0 + ak]);
        As[ak + 0][am] = va.x; As[ak + 1][am] = va.y;
        As[ak + 2][am] = va.z; As[ak + 3][am] = va.w;
#pragma unroll
        for (int p = 0; p < 2; ++p) {
            int idx = tid + p * 256;
            int kk  = idx >> 4;
            int nq  = (idx & 15) * 4;
            *reinterpret_cast<float4*>(&Bs[kk][nq]) =
                *reinterpret_cast<const float4*>(&B[(size_t)(k0 + kk) * 64 + nq]);
        }
        __syncthreads();
#pragma unroll
        for (int k = 0; k < 32; ++k) {
            float a0 = As[k][r0], a1 = As[k][r0 + 1];
            float4 bv = *reinterpret_cast<const float4*>(&Bs[k][c0]);
            acc[0][0] = fmaf(a0, bv.x, acc[0][0]); acc[0][1] = fmaf(a0, bv.y, acc[0][1]);
            acc[0][2] = fmaf(a0, bv.z, acc[0][2]); acc[0][3] = fmaf(a0, bv.w, acc[0][3]);
            acc[1][0] = fmaf(a1, bv.x, acc[1][0]); acc[1][1] = fmaf(a1, bv.y, acc[1][1]);
            acc[1][2] = fmaf(a1, bv.z, acc[1][2]); acc[1][3] = fmaf(a1, bv.w, acc[1][3]);
        }
        __syncthreads();
    }
#pragma unroll
    for (int i = 0; i < 2; ++i) {
        float4 o;
        o.x = acc[i][0] + bias[c0 + 0];
        o.y = acc[i][1] + bias[c0 + 1];
        o.z = acc[i][2] + bias[c0 + 2];
        o.w = acc[i][3] + bias[c0 + 3];
        *reinterpret_cast<float4*>(&C[(size_t)(row0 + r0 + i) * 64 + c0]) = o;
    }
}

// ---------------------------------------------------------------------------
// K2/K3: C[M,1024] = act(A[M,K] @ B[K,1024] + bias)   (M=4096)
// ---------------------------------------------------------------------------
template <bool ACT>
__global__ __launch_bounds__(256) void gemm_n1024(const float* __restrict__ A,
                                                  const float* __restrict__ B,
                                                  const float* __restrict__ bias,
                                                  float* __restrict__ C, int K)
{
    __shared__ alignas(16) float As[32][132];
    __shared__ alignas(16) float Bs[32][128];
    const int tid  = threadIdx.x;
    const int row0 = blockIdx.y * 128;
    const int col0 = blockIdx.x * 128;
    const int tm0  = (tid >> 4) * 4;
    const int tn0  = (tid & 15) * 4;
    float acc[2][2][4][4] = {};
    float4 pa[4], pb[4];

    auto load_regs = [&](int k0) {
#pragma unroll
        for (int p = 0; p < 4; ++p) {
            int idx = tid + p * 256;
            int m   = idx >> 3;
            int kq  = (idx & 7) * 4;
            pa[p] = *reinterpret_cast<const float4*>(&A[(size_t)(row0 + m) * K + k0 + kq]);
            int kk = idx >> 5;
            int nq = (idx & 31) * 4;
            pb[p] = *reinterpret_cast<const float4*>(&B[(size_t)(k0 + kk) * 1024 + col0 + nq]);
        }
    };

    load_regs(0);
    for (int k0 = 0; k0 < K; k0 += 32) {
#pragma unroll
        for (int p = 0; p < 4; ++p) {
            int idx = tid + p * 256;
            int m   = idx >> 3;
            int kq  = (idx & 7) * 4;
            As[kq + 0][m] = pa[p].x; As[kq + 1][m] = pa[p].y;
            As[kq + 2][m] = pa[p].z; As[kq + 3][m] = pa[p].w;
            int kk = idx >> 5;
            int nq = (idx & 31) * 4;
            *reinterpret_cast<float4*>(&Bs[kk][nq]) = pb[p];
        }
        __syncthreads();
        if (k0 + 32 < K) load_regs(k0 + 32);
#pragma unroll
        for (int k = 0; k < 32; ++k) {
            float a[2][4], b[2][4];
            *reinterpret_cast<float4*>(a[0]) = *reinterpret_cast<const float4*>(&As[k][tm0]);
            *reinterpret_cast<float4*>(a[1]) = *reinterpret_cast<const float4*>(&As[k][64 + tm0]);
            *reinterpret_cast<float4*>(b[0]) = *reinterpret_cast<const float4*>(&Bs[k][tn0]);
            *reinterpret_cast<float4*>(b[1]) = *reinterpret_cast<const float4*>(&Bs[k][64 + tn0]);
#pragma unroll
            for (int bi = 0; bi < 2; ++bi)
#pragma unroll
                for (int bj = 0; bj < 2; ++bj)
#pragma unroll
                    for (int i = 0; i < 4; ++i)
#pragma unroll
                        for (int j = 0; j < 4; ++j)
                            acc[bi][bj][i][j] = fmaf(a[bi][i], b[bj][j], acc[bi][bj][i][j]);
        }
        __syncthreads();
    }
#pragma unroll
    for (int bi = 0; bi < 2; ++bi)
#pragma unroll
        for (int i = 0; i < 4; ++i) {
            int rr = row0 + bi * 64 + tm0 + i;
#pragma unroll
            for (int bj = 0; bj < 2; ++bj) {
                int cc = col0 + bj * 64 + tn0;
                float4 o;
                o.x = acc[bi][bj][i][0] + bias[cc + 0];
                o.y = acc[bi][bj][i][1] + bias[cc + 1];
                o.z = acc[bi][bj][i][2] + bias[cc + 2];
                o.w = acc[bi][bj][i][3] + bias[cc + 3];
                if (ACT) { o.x = leaky(o.x); o.y = leaky(o.y); o.z = leaky(o.z); o.w = leaky(o.w); }
                *reinterpret_cast<float4*>(&C[(size_t)rr * 1024 + cc]) = o;
            }
        }
}

// ---------------------------------------------------------------------------
// K4: fused additive chain, restructured for occupancy.
// Grid = (64 row-blocks of BM=64 rows) x (8 r-chunks of 8 r each) = 512 WGs.
// 256 threads: g = tid&15 (rows 4g..4g+3), cg = tid>>4 (cols 4cg..4cg+3).
// Each thread: 4x4 micro-tile per phase; weight float4 feeds 4 rows,
// activation float4 feeds 4 cols. Activations stored in LDS with 16B-unit
// XOR swizzle (colgroup ^ (row>>2)) -> <=2-way conflicts on reads.
// Writes partial t2 [chunk][4096][64] to workspace (reuses dead h1 region).
// ---------------------------------------------------------------------------
#define RCHUNK 8

__global__ __launch_bounds__(256) void fused_tail2(const float* __restrict__ h2,
    const float* __restrict__ a1W, const float* __restrict__ a1b, const float* __restrict__ a1bias,
    const float* __restrict__ a2W, const float* __restrict__ a2b, const float* __restrict__ a2bias,
    const float* __restrict__ Wp2,
    float* __restrict__ partials)
{
    __shared__ alignas(16) float hs[64 * 16];    // h2 slice, swizzled
    __shared__ alignas(16) float w1s[16 * 64];
    __shared__ alignas(16) float w2s[64 * 64];
    __shared__ alignas(16) float wps[64 * 64];
    __shared__ alignas(16) float as_[64 * 64];   // a,  swizzled
    __shared__ alignas(16) float a2s[64 * 64];   // a2, swizzled

    const int tid   = threadIdx.x;
    const int g     = tid & 15;        // row-group: rows 4g..4g+3
    const int cg    = tid >> 4;        // col-group: cols 4cg..4cg+3
    const int c4    = cg * 4;
    const int row0  = blockIdx.x * 64;
    const int rbase = blockIdx.y * RCHUNK;
    const float bias1 = a1bias[0], bias2 = a2bias[0];

    // staging-thread mapping for hs: row_l = tid>>2, colgroup = tid&3
    const int h_row  = tid >> 2;
    const int h_cg   = tid & 3;
    const int h_dst  = h_row * 16 + ((h_cg ^ ((h_row >> 2) & 3)) << 2);

    float4 ph, pw1, pw2[4], pwp[4];
    auto load_stage = [&](int rl) {
        int r = rbase + rl;
        ph  = *reinterpret_cast<const float4*>(
                 &h2[(size_t)(row0 + h_row) * 1024 + r * 16 + h_cg * 4]);
        pw1 = *reinterpret_cast<const float4*>(&a1W[(size_t)r * 1024 + tid * 4]);
#pragma unroll
        for (int p = 0; p < 4; ++p) {
            pw2[p] = *reinterpret_cast<const float4*>(&a2W[(size_t)r * 4096 + (tid + p * 256) * 4]);
            pwp[p] = *reinterpret_cast<const float4*>(&Wp2[(size_t)r * 4096 + (tid + p * 256) * 4]);
        }
    };

    load_stage(0);
    float t2a[4][4] = {};   // [rr][cc] partial t2 for rows 4g+rr, cols c4+cc

    for (int rl = 0; rl < RCHUNK; ++rl) {
        int r = rbase + rl;
        // ---- store staged data to LDS
        *reinterpret_cast<float4*>(&hs[h_dst])    = ph;
        *reinterpret_cast<float4*>(&w1s[tid * 4]) = pw1;
#pragma unroll
        for (int p = 0; p < 4; ++p) {
            *reinterpret_cast<float4*>(&w2s[(tid + p * 256) * 4]) = pw2[p];
            *reinterpret_cast<float4*>(&wps[(tid + p * 256) * 4]) = pwp[p];
        }
        __syncthreads();

        if (rl + 1 < RCHUNK) load_stage(rl + 1);   // prefetch next r during compute

        // ---- phase A: a[64,64] = leaky(hslice[64,16] @ w1 + a1b[r] + bias1)
        {
            float acc[4][4] = {};
#pragma unroll
            for (int k0 = 0; k0 < 16; k0 += 4) {
                float4 hv[4];
#pragma unroll
                for (int rr = 0; rr < 4; ++rr)
                    hv[rr] = *reinterpret_cast<const float4*>(
                        &hs[(4 * g + rr) * 16 + (((k0 >> 2) ^ (g & 3)) << 2)]);
#pragma unroll
                for (int kk = 0; kk < 4; ++kk) {
                    float4 w = *reinterpret_cast<const float4*>(&w1s[(k0 + kk) * 64 + c4]);
#pragma unroll
                    for (int rr = 0; rr < 4; ++rr) {
                        float hval = reinterpret_cast<const float*>(&hv[rr])[kk];
                        acc[rr][0] = fmaf(hval, w.x, acc[rr][0]);
                        acc[rr][1] = fmaf(hval, w.y, acc[rr][1]);
                        acc[rr][2] = fmaf(hval, w.z, acc[rr][2]);
                        acc[rr][3] = fmaf(hval, w.w, acc[rr][3]);
                    }
                }
            }
            float4 ab = *reinterpret_cast<const float4*>(&a1b[r * 64 + c4]);
            int scg = (cg ^ g) << 2;
#pragma unroll
            for (int rr = 0; rr < 4; ++rr) {
                float4 av;
                av.x = leaky(acc[rr][0] + ab.x + bias1);
                av.y = leaky(acc[rr][1] + ab.y + bias1);
                av.z = leaky(acc[rr][2] + ab.z + bias1);
                av.w = leaky(acc[rr][3] + ab.w + bias1);
                *reinterpret_cast<float4*>(&as_[(4 * g + rr) * 64 + scg]) = av;
            }
        }
        __syncthreads();

        // ---- phase B: a2[64,64] = leaky(a @ w2 + a2b[r] + bias2)
        {
            float acc[4][4] = {};
#pragma unroll
            for (int i0 = 0; i0 < 64; i0 += 4) {
                float4 av[4];
#pragma unroll
                for (int rr = 0; rr < 4; ++rr)
                    av[rr] = *reinterpret_cast<const float4*>(
                        &as_[(4 * g + rr) * 64 + (((i0 >> 2) ^ g) << 2)]);
#pragma unroll
                for (int ii = 0; ii < 4; ++ii) {
                    float4 w = *reinterpret_cast<const float4*>(&w2s[(i0 + ii) * 64 + c4]);
#pragma unroll
                    for (int rr = 0; rr < 4; ++rr) {
                        float aval = reinterpret_cast<const float*>(&av[rr])[ii];
                        acc[rr][0] = fmaf(aval, w.x, acc[rr][0]);
                        acc[rr][1] = fmaf(aval, w.y, acc[rr][1]);
                        acc[rr][2] = fmaf(aval, w.z, acc[rr][2]);
                        acc[rr][3] = fmaf(aval, w.w, acc[rr][3]);
                    }
                }
            }
            float4 ab = *reinterpret_cast<const float4*>(&a2b[r * 64 + c4]);
            int scg = (cg ^ g) << 2;
#pragma unroll
            for (int rr = 0; rr < 4; ++rr) {
                float4 av;
                av.x = leaky(acc[rr][0] + ab.x + bias2);
                av.y = leaky(acc[rr][1] + ab.y + bias2);
                av.z = leaky(acc[rr][2] + ab.z + bias2);
                av.w = leaky(acc[rr][3] + ab.w + bias2);
                *reinterpret_cast<float4*>(&a2s[(4 * g + rr) * 64 + scg]) = av;
            }
        }
        __syncthreads();

        // ---- phase C: t2 += a2 @ Wp2[r*64:(r+1)*64, :]
#pragma unroll
        for (int i0 = 0; i0 < 64; i0 += 4) {
            float4 av[4];
#pragma unroll
            for (int rr = 0; rr < 4; ++rr)
                av[rr] = *reinterpret_cast<const float4*>(
                    &a2s[(4 * g + rr) * 64 + (((i0 >> 2) ^ g) << 2)]);
#pragma unroll
            for (int ii = 0; ii < 4; ++ii) {
                float4 w = *reinterpret_cast<const float4*>(&wps[(i0 + ii) * 64 + c4]);
#pragma unroll
                for (int rr = 0; rr < 4; ++rr) {
                    float aval = reinterpret_cast<const float*>(&av[rr])[ii];
                    t2a[rr][0] = fmaf(aval, w.x, t2a[rr][0]);
                    t2a[rr][1] = fmaf(aval, w.y, t2a[rr][1]);
                    t2a[rr][2] = fmaf(aval, w.z, t2a[rr][2]);
                    t2a[rr][3] = fmaf(aval, w.w, t2a[rr][3]);
                }
            }
        }
        __syncthreads();   // protect stage buffers before next overwrite
    }

    // ---- write partial t2 for this r-chunk
#pragma unroll
    for (int rr = 0; rr < 4; ++rr) {
        float4 o; o.x = t2a[rr][0]; o.y = t2a[rr][1]; o.z = t2a[rr][2]; o.w = t2a[rr][3];
        *reinterpret_cast<float4*>(
            &partials[((size_t)blockIdx.y * 4096 + row0 + 4 * g + rr) * 64 + c4]) = o;
    }
}

// ---------------------------------------------------------------------------
// K5: reduce 8 partials + bp2, dot with Wl, add bl -> out[4096]
// 256 threads = 4 rows x 64 lanes.
// ---------------------------------------------------------------------------
__global__ __launch_bounds__(256) void reduce_out(const float* __restrict__ partials,
                                                  const float* __restrict__ bp2,
                                                  const float* __restrict__ Wl,
                                                  const float* __restrict__ bl,
                                                  float* __restrict__ out)
{
    const int tid = threadIdx.x;
    const int row = blockIdx.x * 4 + (tid >> 6);
    const int col = tid & 63;
    float s = bp2[col];
#pragma unroll
    for (int c = 0; c < RCHUNK; ++c)
        s += partials[(size_t)c * 4096 * 64 + (size_t)row * 64 + col];
    s *= Wl[col];
    s += __shfl_xor(s, 1);
    s += __shfl_xor(s, 2);
    s += __shfl_xor(s, 4);
    s += __shfl_xor(s, 8);
    s += __shfl_xor(s, 16);
    s += __shfl_xor(s, 32);
    if (col == 0) out[row] = s + bl[0];
}

// ---------------------------------------------------------------------------
extern "C" void kernel_launch(void* const* d_in, const int* in_sizes, int n_in,
                              void* d_out, int out_size, void* d_ws, size_t ws_size,
                              hipStream_t stream)
{
    const float* x      = (const float*)d_in[0];
    const float* Wpca   = (const float*)d_in[1];
    const float* bpca   = (const float*)d_in[2];
    const float* W1     = (const float*)d_in[3];
    const float* b1     = (const float*)d_in[4];
    const float* W2     = (const float*)d_in[5];
    const float* b2     = (const float*)d_in[6];
    const float* a1W    = (const float*)d_in[7];
    const float* a1b    = (const float*)d_in[8];
    const float* a1bias = (const float*)d_in[9];
    const float* a2W    = (const float*)d_in[10];
    const float* a2b    = (const float*)d_in[11];
    const float* a2bias = (const float*)d_in[12];
    const float* Wp2    = (const float*)d_in[13];
    const float* bp2    = (const float*)d_in[14];
    const float* Wl     = (const float*)d_in[15];
    const float* bl     = (const float*)d_in[16];
    float* out = (float*)d_out;

    float* t  = (float*)d_ws;            // 4096*64
    float* h1 = t  + (size_t)4096 * 64;  // 4096*1024  (reused as partials after K3)
    float* h2 = h1 + (size_t)4096 * 1024;
    float* partials = h1;                // 8*4096*64 floats = 8 MB <= h1's 16 MB

    // t = x @ W_pca + b_pca
    gemm_n64<<<dim3(1, 128), 256, 0, stream>>>(x, Wpca, bpca, t, 1024);
    // h1 = leaky(t @ W1 + b1)
    gemm_n1024<true><<<dim3(8, 32), 256, 0, stream>>>(t, W1, b1, h1, 64);
    // h2 = leaky(h1 @ W2 + b2)
    gemm_n1024<true><<<dim3(8, 32), 256, 0, stream>>>(h1, W2, b2, h2, 1024);
    // fused additive chain -> partial t2 per r-chunk
    fused_tail2<<<dim3(64, 8), 256, 0, stream>>>(h2, a1W, a1b, a1bias,
                                                 a2W, a2b, a2bias, Wp2, partials);
    // reduce partials + PCA2 bias + last layer
    reduce_out<<<dim3(1024), 256, 0, stream>>>(partials, bp2, Wl, bl, out);
}

// Round 4
// 181.672 us; speedup vs baseline: 2.6313x; 1.5865x over previous
//
#include <hip/hip_runtime.h>

#define NEG_SLOPE 0.1f

__device__ __forceinline__ float leaky(float v) { return v > 0.0f ? v : NEG_SLOPE * v; }

typedef _Float16 half8 __attribute__((ext_vector_type(8)));
typedef _Float16 half4v __attribute__((ext_vector_type(4)));
typedef float f32x4 __attribute__((ext_vector_type(4)));

// ---------------------------------------------------------------------------
// K1: C[M,64] = A[M,K] @ B[K,64] + bias        (M=4096, K=1024, N=64), no act
// ---------------------------------------------------------------------------
__global__ __launch_bounds__(256) void gemm_n64(const float* __restrict__ A,
                                                const float* __restrict__ B,
                                                const float* __restrict__ bias,
                                                float* __restrict__ C, int K)
{
    __shared__ alignas(16) float As[32][33];   // [k][m], padded
    __shared__ alignas(16) float Bs[32][64];
    const int tid  = threadIdx.x;
    const int row0 = blockIdx.y * 32;
    const int r0   = (tid >> 4) * 2;
    const int c0   = (tid & 15) * 4;
    const int am   = tid >> 3;
    const int ak   = (tid & 7) * 4;
    float acc[2][4] = {};

    for (int k0 = 0; k0 < K; k0 += 32) {
        float4 va = *reinterpret_cast<const float4*>(&A[(size_t)(row0 + am) * K + k0 + ak]);
        As[ak + 0][am] = va.x; As[ak + 1][am] = va.y;
        As[ak + 2][am] = va.z; As[ak + 3][am] = va.w;
#pragma unroll
        for (int p = 0; p < 2; ++p) {
            int idx = tid + p * 256;
            int kk  = idx >> 4;
            int nq  = (idx & 15) * 4;
            *reinterpret_cast<float4*>(&Bs[kk][nq]) =
                *reinterpret_cast<const float4*>(&B[(size_t)(k0 + kk) * 64 + nq]);
        }
        __syncthreads();
#pragma unroll
        for (int k = 0; k < 32; ++k) {
            float a0 = As[k][r0], a1 = As[k][r0 + 1];
            float4 bv = *reinterpret_cast<const float4*>(&Bs[k][c0]);
            acc[0][0] = fmaf(a0, bv.x, acc[0][0]); acc[0][1] = fmaf(a0, bv.y, acc[0][1]);
            acc[0][2] = fmaf(a0, bv.z, acc[0][2]); acc[0][3] = fmaf(a0, bv.w, acc[0][3]);
            acc[1][0] = fmaf(a1, bv.x, acc[1][0]); acc[1][1] = fmaf(a1, bv.y, acc[1][1]);
            acc[1][2] = fmaf(a1, bv.z, acc[1][2]); acc[1][3] = fmaf(a1, bv.w, acc[1][3]);
        }
        __syncthreads();
    }
#pragma unroll
    for (int i = 0; i < 2; ++i) {
        float4 o;
        o.x = acc[i][0] + bias[c0 + 0];
        o.y = acc[i][1] + bias[c0 + 1];
        o.z = acc[i][2] + bias[c0 + 2];
        o.w = acc[i][3] + bias[c0 + 3];
        *reinterpret_cast<float4*>(&C[(size_t)(row0 + r0 + i) * 64 + c0]) = o;
    }
}

// ---------------------------------------------------------------------------
// K2: C[M,1024] = leaky(A[M,K] @ B[K,1024] + bias)  -> fp16 output (h1)
// ---------------------------------------------------------------------------
__global__ __launch_bounds__(256) void gemm_n1024_f16out(const float* __restrict__ A,
                                                         const float* __restrict__ B,
                                                         const float* __restrict__ bias,
                                                         _Float16* __restrict__ C, int K)
{
    __shared__ alignas(16) float As[32][132];
    __shared__ alignas(16) float Bs[32][128];
    const int tid  = threadIdx.x;
    const int row0 = blockIdx.y * 128;
    const int col0 = blockIdx.x * 128;
    const int tm0  = (tid >> 4) * 4;
    const int tn0  = (tid & 15) * 4;
    float acc[2][2][4][4] = {};
    float4 pa[4], pb[4];

    auto load_regs = [&](int k0) {
#pragma unroll
        for (int p = 0; p < 4; ++p) {
            int idx = tid + p * 256;
            int m   = idx >> 3;
            int kq  = (idx & 7) * 4;
            pa[p] = *reinterpret_cast<const float4*>(&A[(size_t)(row0 + m) * K + k0 + kq]);
            int kk = idx >> 5;
            int nq = (idx & 31) * 4;
            pb[p] = *reinterpret_cast<const float4*>(&B[(size_t)(k0 + kk) * 1024 + col0 + nq]);
        }
    };

    load_regs(0);
    for (int k0 = 0; k0 < K; k0 += 32) {
#pragma unroll
        for (int p = 0; p < 4; ++p) {
            int idx = tid + p * 256;
            int m   = idx >> 3;
            int kq  = (idx & 7) * 4;
            As[kq + 0][m] = pa[p].x; As[kq + 1][m] = pa[p].y;
            As[kq + 2][m] = pa[p].z; As[kq + 3][m] = pa[p].w;
            int kk = idx >> 5;
            int nq = (idx & 31) * 4;
            *reinterpret_cast<float4*>(&Bs[kk][nq]) = pb[p];
        }
        __syncthreads();
        if (k0 + 32 < K) load_regs(k0 + 32);
#pragma unroll
        for (int k = 0; k < 32; ++k) {
            float a[2][4], b[2][4];
            *reinterpret_cast<float4*>(a[0]) = *reinterpret_cast<const float4*>(&As[k][tm0]);
            *reinterpret_cast<float4*>(a[1]) = *reinterpret_cast<const float4*>(&As[k][64 + tm0]);
            *reinterpret_cast<float4*>(b[0]) = *reinterpret_cast<const float4*>(&Bs[k][tn0]);
            *reinterpret_cast<float4*>(b[1]) = *reinterpret_cast<const float4*>(&Bs[k][64 + tn0]);
#pragma unroll
            for (int bi = 0; bi < 2; ++bi)
#pragma unroll
                for (int bj = 0; bj < 2; ++bj)
#pragma unroll
                    for (int i = 0; i < 4; ++i)
#pragma unroll
                        for (int j = 0; j < 4; ++j)
                            acc[bi][bj][i][j] = fmaf(a[bi][i], b[bj][j], acc[bi][bj][i][j]);
        }
        __syncthreads();
    }
#pragma unroll
    for (int bi = 0; bi < 2; ++bi)
#pragma unroll
        for (int i = 0; i < 4; ++i) {
            int rr = row0 + bi * 64 + tm0 + i;
#pragma unroll
            for (int bj = 0; bj < 2; ++bj) {
                int cc = col0 + bj * 64 + tn0;
                half4v o;
                o[0] = (_Float16)leaky(acc[bi][bj][i][0] + bias[cc + 0]);
                o[1] = (_Float16)leaky(acc[bi][bj][i][1] + bias[cc + 1]);
                o[2] = (_Float16)leaky(acc[bi][bj][i][2] + bias[cc + 2]);
                o[3] = (_Float16)leaky(acc[bi][bj][i][3] + bias[cc + 3]);
                *reinterpret_cast<half4v*>(&C[(size_t)rr * 1024 + cc]) = o;
            }
        }
}

// ---------------------------------------------------------------------------
// K2b: W2T[n][k] = (fp16) W2[k][n]    (1024x1024 transpose + convert)
// ---------------------------------------------------------------------------
__global__ __launch_bounds__(256) void transpose_f16(const float* __restrict__ W,
                                                     _Float16* __restrict__ WT)
{
    __shared__ float tile[32][33];
    const int tid = threadIdx.x;
    const int k0  = blockIdx.y * 32;
    const int n0  = blockIdx.x * 32;
    const int r   = tid >> 3;
    const int c   = (tid & 7) * 4;
    float4 v = *reinterpret_cast<const float4*>(&W[(size_t)(k0 + r) * 1024 + n0 + c]);
    tile[r][c + 0] = v.x; tile[r][c + 1] = v.y; tile[r][c + 2] = v.z; tile[r][c + 3] = v.w;
    __syncthreads();
    half4v o;
    o[0] = (_Float16)tile[c + 0][r];
    o[1] = (_Float16)tile[c + 1][r];
    o[2] = (_Float16)tile[c + 2][r];
    o[3] = (_Float16)tile[c + 3][r];
    *reinterpret_cast<half4v*>(&WT[(size_t)(n0 + r) * 1024 + k0 + c]) = o;
}

// ---------------------------------------------------------------------------
// K3: h2[4096,1024] = leaky(h1[4096,1024] @ W2 + b2) via fp16 MFMA.
// A = h1 fp16 [M][K]; BT = W2^T fp16 [N][K]; C fp32.
// 128x128 tile, BK=32, 4 waves (2x2), 16x 16x16x32 MFMA per wave per K-step.
// global_load_lds width=16 staging, linear LDS dest + XOR-swizzled global
// source; ds_read_b128 frag loads use the same XOR (slot ^ (row&3)).
// ---------------------------------------------------------------------------
__global__ __launch_bounds__(256) void gemm_mfma_f16(const _Float16* __restrict__ A,
                                                     const _Float16* __restrict__ BT,
                                                     const float* __restrict__ bias,
                                                     float* __restrict__ C)
{
    __shared__ alignas(16) _Float16 As[128 * 32];
    __shared__ alignas(16) _Float16 Bs[128 * 32];
    const int tid = threadIdx.x;
    const int l   = tid & 63;
    const int w   = tid >> 6;          // wave 0..3
    const int wm  = w >> 1;            // wave row (2)
    const int wn  = w & 1;             // wave col (2)
    const int bm0 = blockIdx.y * 128;
    const int bn0 = blockIdx.x * 128;
    const int fr  = l & 15;            // fragment row/col within 16-tile
    const int fg  = l >> 4;            // k-group 0..3
    const int srow  = l >> 2;          // staging: row within 16-row issue
    const int sslot = l & 3;           // staging: 16B slot within 64B row

    f32x4 acc[4][4] = {};

    for (int k0 = 0; k0 < 1024; k0 += 32) {
#pragma unroll
        for (int i = 0; i < 2; ++i) {
            const int r0   = (w * 2 + i) * 16;          // wave-uniform
            const int rowA = r0 + srow;
            const int slot = sslot ^ (rowA & 3);        // pre-swizzled source
            const _Float16* ga = &A[(size_t)(bm0 + rowA) * 1024 + k0 + slot * 8];
            __builtin_amdgcn_global_load_lds(
                (const __attribute__((address_space(1))) void*)ga,
                (__attribute__((address_space(3))) void*)&As[r0 * 32], 16, 0, 0);
            const _Float16* gb = &BT[(size_t)(bn0 + rowA) * 1024 + k0 + slot * 8];
            __builtin_amdgcn_global_load_lds(
                (const __attribute__((address_space(1))) void*)gb,
                (__attribute__((address_space(3))) void*)&Bs[r0 * 32], 16, 0, 0);
        }
        __syncthreads();   // drains vmcnt

        half8 af[4], bf[4];
#pragma unroll
        for (int mt = 0; mt < 4; ++mt) {
            int row = wm * 64 + mt * 16 + fr;
            af[mt] = *reinterpret_cast<const half8*>(&As[row * 32 + ((fg ^ (row & 3)) << 3)]);
        }
#pragma unroll
        for (int nt = 0; nt < 4; ++nt) {
            int row = wn * 64 + nt * 16 + fr;
            bf[nt] = *reinterpret_cast<const half8*>(&Bs[row * 32 + ((fg ^ (row & 3)) << 3)]);
        }
#pragma unroll
        for (int mt = 0; mt < 4; ++mt)
#pragma unroll
            for (int nt = 0; nt < 4; ++nt)
                acc[mt][nt] = __builtin_amdgcn_mfma_f32_16x16x32_f16(af[mt], bf[nt],
                                                                     acc[mt][nt], 0, 0, 0);
        __syncthreads();   // protect LDS before next stage
    }

    // epilogue: C/D layout col = lane&15, row = (lane>>4)*4 + reg
#pragma unroll
    for (int nt = 0; nt < 4; ++nt) {
        const int col = bn0 + wn * 64 + nt * 16 + fr;
        const float bv = bias[col];
#pragma unroll
        for (int mt = 0; mt < 4; ++mt) {
#pragma unroll
            for (int r = 0; r < 4; ++r) {
                const int row = bm0 + wm * 64 + mt * 16 + fg * 4 + r;
                C[(size_t)row * 1024 + col] = leaky(acc[mt][nt][r] + bv);
            }
        }
    }
}

// ---------------------------------------------------------------------------
// K4: fused additive chain (unchanged from round 2)
// ---------------------------------------------------------------------------
#define RCHUNK 8

__global__ __launch_bounds__(256) void fused_tail2(const float* __restrict__ h2,
    const float* __restrict__ a1W, const float* __restrict__ a1b, const float* __restrict__ a1bias,
    const float* __restrict__ a2W, const float* __restrict__ a2b, const float* __restrict__ a2bias,
    const float* __restrict__ Wp2,
    float* __restrict__ partials)
{
    __shared__ alignas(16) float hs[64 * 16];
    __shared__ alignas(16) float w1s[16 * 64];
    __shared__ alignas(16) float w2s[64 * 64];
    __shared__ alignas(16) float wps[64 * 64];
    __shared__ alignas(16) float as_[64 * 64];
    __shared__ alignas(16) float a2s[64 * 64];

    const int tid   = threadIdx.x;
    const int g     = tid & 15;
    const int cg    = tid >> 4;
    const int c4    = cg * 4;
    const int row0  = blockIdx.x * 64;
    const int rbase = blockIdx.y * RCHUNK;
    const float bias1 = a1bias[0], bias2 = a2bias[0];

    const int h_row  = tid >> 2;
    const int h_cg   = tid & 3;
    const int h_dst  = h_row * 16 + ((h_cg ^ ((h_row >> 2) & 3)) << 2);

    float4 ph, pw1, pw2[4], pwp[4];
    auto load_stage = [&](int rl) {
        int r = rbase + rl;
        ph  = *reinterpret_cast<const float4*>(
                 &h2[(size_t)(row0 + h_row) * 1024 + r * 16 + h_cg * 4]);
        pw1 = *reinterpret_cast<const float4*>(&a1W[(size_t)r * 1024 + tid * 4]);
#pragma unroll
        for (int p = 0; p < 4; ++p) {
            pw2[p] = *reinterpret_cast<const float4*>(&a2W[(size_t)r * 4096 + (tid + p * 256) * 4]);
            pwp[p] = *reinterpret_cast<const float4*>(&Wp2[(size_t)r * 4096 + (tid + p * 256) * 4]);
        }
    };

    load_stage(0);
    float t2a[4][4] = {};

    for (int rl = 0; rl < RCHUNK; ++rl) {
        int r = rbase + rl;
        *reinterpret_cast<float4*>(&hs[h_dst])    = ph;
        *reinterpret_cast<float4*>(&w1s[tid * 4]) = pw1;
#pragma unroll
        for (int p = 0; p < 4; ++p) {
            *reinterpret_cast<float4*>(&w2s[(tid + p * 256) * 4]) = pw2[p];
            *reinterpret_cast<float4*>(&wps[(tid + p * 256) * 4]) = pwp[p];
        }
        __syncthreads();

        if (rl + 1 < RCHUNK) load_stage(rl + 1);

        {
            float acc[4][4] = {};
#pragma unroll
            for (int k0 = 0; k0 < 16; k0 += 4) {
                float4 hv[4];
#pragma unroll
                for (int rr = 0; rr < 4; ++rr)
                    hv[rr] = *reinterpret_cast<const float4*>(
                        &hs[(4 * g + rr) * 16 + (((k0 >> 2) ^ (g & 3)) << 2)]);
#pragma unroll
                for (int kk = 0; kk < 4; ++kk) {
                    float4 wv = *reinterpret_cast<const float4*>(&w1s[(k0 + kk) * 64 + c4]);
#pragma unroll
                    for (int rr = 0; rr < 4; ++rr) {
                        float hval = reinterpret_cast<const float*>(&hv[rr])[kk];
                        acc[rr][0] = fmaf(hval, wv.x, acc[rr][0]);
                        acc[rr][1] = fmaf(hval, wv.y, acc[rr][1]);
                        acc[rr][2] = fmaf(hval, wv.z, acc[rr][2]);
                        acc[rr][3] = fmaf(hval, wv.w, acc[rr][3]);
                    }
                }
            }
            float4 ab = *reinterpret_cast<const float4*>(&a1b[r * 64 + c4]);
            int scg = (cg ^ g) << 2;
#pragma unroll
            for (int rr = 0; rr < 4; ++rr) {
                float4 av;
                av.x = leaky(acc[rr][0] + ab.x + bias1);
                av.y = leaky(acc[rr][1] + ab.y + bias1);
                av.z = leaky(acc[rr][2] + ab.z + bias1);
                av.w = leaky(acc[rr][3] + ab.w + bias1);
                *reinterpret_cast<float4*>(&as_[(4 * g + rr) * 64 + scg]) = av;
            }
        }
        __syncthreads();

        {
            float acc[4][4] = {};
#pragma unroll
            for (int i0 = 0; i0 < 64; i0 += 4) {
                float4 av[4];
#pragma unroll
                for (int rr = 0; rr < 4; ++rr)
                    av[rr] = *reinterpret_cast<const float4*>(
                        &as_[(4 * g + rr) * 64 + (((i0 >> 2) ^ g) << 2)]);
#pragma unroll
                for (int ii = 0; ii < 4; ++ii) {
                    float4 wv = *reinterpret_cast<const float4*>(&w2s[(i0 + ii) * 64 + c4]);
#pragma unroll
                    for (int rr = 0; rr < 4; ++rr) {
                        float aval = reinterpret_cast<const float*>(&av[rr])[ii];
                        acc[rr][0] = fmaf(aval, wv.x, acc[rr][0]);
                        acc[rr][1] = fmaf(aval, wv.y, acc[rr][1]);
                        acc[rr][2] = fmaf(aval, wv.z, acc[rr][2]);
                        acc[rr][3] = fmaf(aval, wv.w, acc[rr][3]);
                    }
                }
            }
            float4 ab = *reinterpret_cast<const float4*>(&a2b[r * 64 + c4]);
            int scg = (cg ^ g) << 2;
#pragma unroll
            for (int rr = 0; rr < 4; ++rr) {
                float4 av;
                av.x = leaky(acc[rr][0] + ab.x + bias2);
                av.y = leaky(acc[rr][1] + ab.y + bias2);
                av.z = leaky(acc[rr][2] + ab.z + bias2);
                av.w = leaky(acc[rr][3] + ab.w + bias2);
                *reinterpret_cast<float4*>(&a2s[(4 * g + rr) * 64 + scg]) = av;
            }
        }
        __syncthreads();

#pragma unroll
        for (int i0 = 0; i0 < 64; i0 += 4) {
            float4 av[4];
#pragma unroll
            for (int rr = 0; rr < 4; ++rr)
                av[rr] = *reinterpret_cast<const float4*>(
                    &a2s[(4 * g + rr) * 64 + (((i0 >> 2) ^ g) << 2)]);
#pragma unroll
            for (int ii = 0; ii < 4; ++ii) {
                float4 wv = *reinterpret_cast<const float4*>(&wps[(i0 + ii) * 64 + c4]);
#pragma unroll
                for (int rr = 0; rr < 4; ++rr) {
                    float aval = reinterpret_cast<const float*>(&av[rr])[ii];
                    t2a[rr][0] = fmaf(aval, wv.x, t2a[rr][0]);
                    t2a[rr][1] = fmaf(aval, wv.y, t2a[rr][1]);
                    t2a[rr][2] = fmaf(aval, wv.z, t2a[rr][2]);
                    t2a[rr][3] = fmaf(aval, wv.w, t2a[rr][3]);
                }
            }
        }
        __syncthreads();
    }

#pragma unroll
    for (int rr = 0; rr < 4; ++rr) {
        float4 o; o.x = t2a[rr][0]; o.y = t2a[rr][1]; o.z = t2a[rr][2]; o.w = t2a[rr][3];
        *reinterpret_cast<float4*>(
            &partials[((size_t)blockIdx.y * 4096 + row0 + 4 * g + rr) * 64 + c4]) = o;
    }
}

// ---------------------------------------------------------------------------
// K5: reduce partials + bp2, dot with Wl, add bl -> out[4096]
// ---------------------------------------------------------------------------
__global__ __launch_bounds__(256) void reduce_out(const float* __restrict__ partials,
                                                  const float* __restrict__ bp2,
                                                  const float* __restrict__ Wl,
                                                  const float* __restrict__ bl,
                                                  float* __restrict__ out)
{
    const int tid = threadIdx.x;
    const int row = blockIdx.x * 4 + (tid >> 6);
    const int col = tid & 63;
    float s = bp2[col];
#pragma unroll
    for (int c = 0; c < RCHUNK; ++c)
        s += partials[(size_t)c * 4096 * 64 + (size_t)row * 64 + col];
    s *= Wl[col];
    s += __shfl_xor(s, 1);
    s += __shfl_xor(s, 2);
    s += __shfl_xor(s, 4);
    s += __shfl_xor(s, 8);
    s += __shfl_xor(s, 16);
    s += __shfl_xor(s, 32);
    if (col == 0) out[row] = s + bl[0];
}

// ---------------------------------------------------------------------------
extern "C" void kernel_launch(void* const* d_in, const int* in_sizes, int n_in,
                              void* d_out, int out_size, void* d_ws, size_t ws_size,
                              hipStream_t stream)
{
    const float* x      = (const float*)d_in[0];
    const float* Wpca   = (const float*)d_in[1];
    const float* bpca   = (const float*)d_in[2];
    const float* W1     = (const float*)d_in[3];
    const float* b1     = (const float*)d_in[4];
    const float* W2     = (const float*)d_in[5];
    const float* b2     = (const float*)d_in[6];
    const float* a1W    = (const float*)d_in[7];
    const float* a1b    = (const float*)d_in[8];
    const float* a1bias = (const float*)d_in[9];
    const float* a2W    = (const float*)d_in[10];
    const float* a2b    = (const float*)d_in[11];
    const float* a2bias = (const float*)d_in[12];
    const float* Wp2    = (const float*)d_in[13];
    const float* bp2    = (const float*)d_in[14];
    const float* Wl     = (const float*)d_in[15];
    const float* bl     = (const float*)d_in[16];
    float* out = (float*)d_out;

    // workspace layout
    float*    t    = (float*)d_ws;                                 // 1 MB
    _Float16* h1h  = (_Float16*)(t + (size_t)4096 * 64);           // 8 MB fp16
    float*    h2   = (float*)((char*)h1h + (size_t)4096 * 1024 * 2); // 16 MB
    _Float16* W2T  = (_Float16*)(h2 + (size_t)4096 * 1024);        // 2 MB fp16
    float* partials = (float*)h1h;                                 // reuse (8 MB), dead after K3

    // W2^T fp16 (no deps)
    transpose_f16<<<dim3(32, 32), 256, 0, stream>>>(W2, W2T);
    // t = x @ W_pca + b_pca
    gemm_n64<<<dim3(1, 128), 256, 0, stream>>>(x, Wpca, bpca, t, 1024);
    // h1 = leaky(t @ W1 + b1)  -> fp16
    gemm_n1024_f16out<<<dim3(8, 32), 256, 0, stream>>>(t, W1, b1, h1h, 64);
    // h2 = leaky(h1 @ W2 + b2)  via fp16 MFMA
    gemm_mfma_f16<<<dim3(8, 32), 256, 0, stream>>>(h1h, W2T, b2, h2);
    // fused additive chain -> partial t2 per r-chunk
    fused_tail2<<<dim3(64, 8), 256, 0, stream>>>(h2, a1W, a1b, a1bias,
                                                 a2W, a2b, a2bias, Wp2, partials);
    // reduce partials + PCA2 bias + last layer
    reduce_out<<<dim3(1024), 256, 0, stream>>>(partials, bp2, Wl, bl, out);
}

// Round 5
// 111.976 us; speedup vs baseline: 4.2690x; 1.6224x over previous
//
#include <hip/hip_runtime.h>

#define NEG_SLOPE 0.1f

__device__ __forceinline__ float leaky(float v) { return v > 0.0f ? v : NEG_SLOPE * v; }

typedef _Float16 h4_t __attribute__((ext_vector_type(4)));
typedef _Float16 h8_t __attribute__((ext_vector_type(8)));
typedef float f32x4 __attribute__((ext_vector_type(4)));

__device__ __forceinline__ unsigned lds_off(const void* p) {
    return (unsigned)(unsigned long long)p;   // low 32 bits of generic LDS ptr = DS offset
}

__device__ __forceinline__ void lgkm0() {
    asm volatile("s_waitcnt lgkmcnt(0)" ::: "memory");
    __builtin_amdgcn_sched_barrier(0);        // rule #18: keep MFMA below the wait
}

__device__ __forceinline__ h4_t tr16(unsigned addr) {
    h4_t d;
    asm volatile("ds_read_b64_tr_b16 %0, %1" : "=v"(d) : "v"(addr) : "memory");
    return d;
}

// ---------------------------------------------------------------------------
// K1: C[M,64] = A[M,K] @ B[K,64] + bias        (M=4096, K=1024, N=64)
// ---------------------------------------------------------------------------
__global__ __launch_bounds__(256) void gemm_n64(const float* __restrict__ A,
                                                const float* __restrict__ B,
                                                const float* __restrict__ bias,
                                                float* __restrict__ C, int K)
{
    __shared__ alignas(16) float As[32][33];
    __shared__ alignas(16) float Bs[32][64];
    const int tid  = threadIdx.x;
    const int row0 = blockIdx.y * 32;
    const int r0   = (tid >> 4) * 2;
    const int c0   = (tid & 15) * 4;
    const int am   = tid >> 3;
    const int ak   = (tid & 7) * 4;
    float acc[2][4] = {};

    for (int k0 = 0; k0 < K; k0 += 32) {
        float4 va = *reinterpret_cast<const float4*>(&A[(size_t)(row0 + am) * K + k0 + ak]);
        As[ak + 0][am] = va.x; As[ak + 1][am] = va.y;
        As[ak + 2][am] = va.z; As[ak + 3][am] = va.w;
#pragma unroll
        for (int p = 0; p < 2; ++p) {
            int idx = tid + p * 256;
            int kk  = idx >> 4;
            int nq  = (idx & 15) * 4;
            *reinterpret_cast<float4*>(&Bs[kk][nq]) =
                *reinterpret_cast<const float4*>(&B[(size_t)(k0 + kk) * 64 + nq]);
        }
        __syncthreads();
#pragma unroll
        for (int k = 0; k < 32; ++k) {
            float a0 = As[k][r0], a1 = As[k][r0 + 1];
            float4 bv = *reinterpret_cast<const float4*>(&Bs[k][c0]);
            acc[0][0] = fmaf(a0, bv.x, acc[0][0]); acc[0][1] = fmaf(a0, bv.y, acc[0][1]);
            acc[0][2] = fmaf(a0, bv.z, acc[0][2]); acc[0][3] = fmaf(a0, bv.w, acc[0][3]);
            acc[1][0] = fmaf(a1, bv.x, acc[1][0]); acc[1][1] = fmaf(a1, bv.y, acc[1][1]);
            acc[1][2] = fmaf(a1, bv.z, acc[1][2]); acc[1][3] = fmaf(a1, bv.w, acc[1][3]);
        }
        __syncthreads();
    }
#pragma unroll
    for (int i = 0; i < 2; ++i) {
        float4 o;
        o.x = acc[i][0] + bias[c0 + 0];
        o.y = acc[i][1] + bias[c0 + 1];
        o.z = acc[i][2] + bias[c0 + 2];
        o.w = acc[i][3] + bias[c0 + 3];
        *reinterpret_cast<float4*>(&C[(size_t)(row0 + r0 + i) * 64 + c0]) = o;
    }
}

// ---------------------------------------------------------------------------
// K2: h1[M,1024] = leaky(t[M,64] @ W1 + b1)  -> fp16
// ---------------------------------------------------------------------------
__global__ __launch_bounds__(256) void gemm_n1024_f16out(const float* __restrict__ A,
                                                         const float* __restrict__ B,
                                                         const float* __restrict__ bias,
                                                         _Float16* __restrict__ C, int K)
{
    __shared__ alignas(16) float As[32][132];
    __shared__ alignas(16) float Bs[32][128];
    const int tid  = threadIdx.x;
    const int row0 = blockIdx.y * 128;
    const int col0 = blockIdx.x * 128;
    const int tm0  = (tid >> 4) * 4;
    const int tn0  = (tid & 15) * 4;
    float acc[2][2][4][4] = {};
    float4 pa[4], pb[4];

    auto load_regs = [&](int k0) {
#pragma unroll
        for (int p = 0; p < 4; ++p) {
            int idx = tid + p * 256;
            int m   = idx >> 3;
            int kq  = (idx & 7) * 4;
            pa[p] = *reinterpret_cast<const float4*>(&A[(size_t)(row0 + m) * K + k0 + kq]);
            int kk = idx >> 5;
            int nq = (idx & 31) * 4;
            pb[p] = *reinterpret_cast<const float4*>(&B[(size_t)(k0 + kk) * 1024 + col0 + nq]);
        }
    };

    load_regs(0);
    for (int k0 = 0; k0 < K; k0 += 32) {
#pragma unroll
        for (int p = 0; p < 4; ++p) {
            int idx = tid + p * 256;
            int m   = idx >> 3;
            int kq  = (idx & 7) * 4;
            As[kq + 0][m] = pa[p].x; As[kq + 1][m] = pa[p].y;
            As[kq + 2][m] = pa[p].z; As[kq + 3][m] = pa[p].w;
            int kk = idx >> 5;
            int nq = (idx & 31) * 4;
            *reinterpret_cast<float4*>(&Bs[kk][nq]) = pb[p];
        }
        __syncthreads();
        if (k0 + 32 < K) load_regs(k0 + 32);
#pragma unroll
        for (int k = 0; k < 32; ++k) {
            float a[2][4], b[2][4];
            *reinterpret_cast<float4*>(a[0]) = *reinterpret_cast<const float4*>(&As[k][tm0]);
            *reinterpret_cast<float4*>(a[1]) = *reinterpret_cast<const float4*>(&As[k][64 + tm0]);
            *reinterpret_cast<float4*>(b[0]) = *reinterpret_cast<const float4*>(&Bs[k][tn0]);
            *reinterpret_cast<float4*>(b[1]) = *reinterpret_cast<const float4*>(&Bs[k][64 + tn0]);
#pragma unroll
            for (int bi = 0; bi < 2; ++bi)
#pragma unroll
                for (int bj = 0; bj < 2; ++bj)
#pragma unroll
                    for (int i = 0; i < 4; ++i)
#pragma unroll
                        for (int j = 0; j < 4; ++j)
                            acc[bi][bj][i][j] = fmaf(a[bi][i], b[bj][j], acc[bi][bj][i][j]);
        }
        __syncthreads();
    }
#pragma unroll
    for (int bi = 0; bi < 2; ++bi)
#pragma unroll
        for (int i = 0; i < 4; ++i) {
            int rr = row0 + bi * 64 + tm0 + i;
#pragma unroll
            for (int bj = 0; bj < 2; ++bj) {
                int cc = col0 + bj * 64 + tn0;
                h4_t o;
                o[0] = (_Float16)leaky(acc[bi][bj][i][0] + bias[cc + 0]);
                o[1] = (_Float16)leaky(acc[bi][bj][i][1] + bias[cc + 1]);
                o[2] = (_Float16)leaky(acc[bi][bj][i][2] + bias[cc + 2]);
                o[3] = (_Float16)leaky(acc[bi][bj][i][3] + bias[cc + 3]);
                *reinterpret_cast<h4_t*>(&C[(size_t)rr * 1024 + cc]) = o;
            }
        }
}

// ---------------------------------------------------------------------------
// K2b: W2T[n][k] = (fp16) W2[k][n]
// ---------------------------------------------------------------------------
__global__ __launch_bounds__(256) void transpose_f16(const float* __restrict__ W,
                                                     _Float16* __restrict__ WT)
{
    __shared__ float tile[32][33];
    const int tid = threadIdx.x;
    const int k0  = blockIdx.y * 32;
    const int n0  = blockIdx.x * 32;
    const int r   = tid >> 3;
    const int c   = (tid & 7) * 4;
    float4 v = *reinterpret_cast<const float4*>(&W[(size_t)(k0 + r) * 1024 + n0 + c]);
    tile[r][c + 0] = v.x; tile[r][c + 1] = v.y; tile[r][c + 2] = v.z; tile[r][c + 3] = v.w;
    __syncthreads();
    h4_t o;
    o[0] = (_Float16)tile[c + 0][r];
    o[1] = (_Float16)tile[c + 1][r];
    o[2] = (_Float16)tile[c + 2][r];
    o[3] = (_Float16)tile[c + 3][r];
    *reinterpret_cast<h4_t*>(&WT[(size_t)(n0 + r) * 1024 + k0 + c]) = o;
}

// ---------------------------------------------------------------------------
// K2c: pack tail weights into MFMA B-fragment order, fp16.
// wpack[r] (9216 fp16 = 18KB): [0,1024) w1 frags (16x16x16: n=l&15, k=(l>>4)*4+j)
//                              [1024,5120) w2 frags (16x16x32: kt,nt,l,j)
//                              [5120,9216) wp frags (same shape)
// ---------------------------------------------------------------------------
__global__ __launch_bounds__(256) void pack_tail_weights(const float* __restrict__ a1W,
                                                         const float* __restrict__ a2W,
                                                         const float* __restrict__ Wp2,
                                                         _Float16* __restrict__ wpack)
{
    const int tid = blockIdx.x * 256 + threadIdx.x;   // < 589824
    const int r = tid / 9216, qq = tid % 9216;
    float v;
    if (qq < 1024) {
        int nt = qq >> 8, rem = qq & 255, l = rem >> 2, j = rem & 3;
        int n = nt * 16 + (l & 15), k = (l >> 4) * 4 + j;
        v = a1W[(size_t)r * 1024 + k * 64 + n];
    } else if (qq < 5120) {
        int p = qq - 1024, kt = p >> 11, u = p & 2047, nt = u >> 9, s = u & 511, l = s >> 3, j = s & 7;
        int n = nt * 16 + (l & 15), k = kt * 32 + (l >> 4) * 8 + j;
        v = a2W[(size_t)r * 4096 + k * 64 + n];
    } else {
        int p = qq - 5120, kt = p >> 11, u = p & 2047, nt = u >> 9, s = u & 511, l = s >> 3, j = s & 7;
        int n = nt * 16 + (l & 15), k = kt * 32 + (l >> 4) * 8 + j;
        v = Wp2[((size_t)r * 64 + k) * 64 + n];
    }
    wpack[tid] = (_Float16)v;
}

// ---------------------------------------------------------------------------
// K3: h2 = leaky(h1 @ W2 + b2) via fp16 MFMA; output written PACKED:
// h2t[cblk(64)][rblk(256)][k(16)][row(16)] fp16  (k-major per 16x16 tile,
// i.e. exactly the ds_read_b64_tr_b16 A-fragment source layout).
// ---------------------------------------------------------------------------
__global__ __launch_bounds__(256) void gemm_mfma_f16(const _Float16* __restrict__ A,
                                                     const _Float16* __restrict__ BT,
                                                     const float* __restrict__ bias,
                                                     _Float16* __restrict__ h2t)
{
    __shared__ alignas(16) _Float16 As[128 * 32];
    __shared__ alignas(16) _Float16 Bs[128 * 32];
    const int tid = threadIdx.x;
    const int l   = tid & 63;
    const int w   = tid >> 6;
    const int wm  = w >> 1;
    const int wn  = w & 1;
    const int bm0 = blockIdx.y * 128;
    const int bn0 = blockIdx.x * 128;
    const int fr  = l & 15;
    const int fg  = l >> 4;
    const int srow  = l >> 2;
    const int sslot = l & 3;

    f32x4 acc[4][4] = {};

    for (int k0 = 0; k0 < 1024; k0 += 32) {
#pragma unroll
        for (int i = 0; i < 2; ++i) {
            const int r0   = (w * 2 + i) * 16;
            const int rowA = r0 + srow;
            const int slot = sslot ^ (rowA & 3);
            const _Float16* ga = &A[(size_t)(bm0 + rowA) * 1024 + k0 + slot * 8];
            __builtin_amdgcn_global_load_lds(
                (const __attribute__((address_space(1))) void*)ga,
                (__attribute__((address_space(3))) void*)&As[r0 * 32], 16, 0, 0);
            const _Float16* gb = &BT[(size_t)(bn0 + rowA) * 1024 + k0 + slot * 8];
            __builtin_amdgcn_global_load_lds(
                (const __attribute__((address_space(1))) void*)gb,
                (__attribute__((address_space(3))) void*)&Bs[r0 * 32], 16, 0, 0);
        }
        __syncthreads();

        h8_t af[4], bf[4];
#pragma unroll
        for (int mt = 0; mt < 4; ++mt) {
            int row = wm * 64 + mt * 16 + fr;
            af[mt] = *reinterpret_cast<const h8_t*>(&As[row * 32 + ((fg ^ (row & 3)) << 3)]);
        }
#pragma unroll
        for (int nt = 0; nt < 4; ++nt) {
            int row = wn * 64 + nt * 16 + fr;
            bf[nt] = *reinterpret_cast<const h8_t*>(&Bs[row * 32 + ((fg ^ (row & 3)) << 3)]);
        }
#pragma unroll
        for (int mt = 0; mt < 4; ++mt)
#pragma unroll
            for (int nt = 0; nt < 4; ++nt)
                acc[mt][nt] = __builtin_amdgcn_mfma_f32_16x16x32_f16(af[mt], bf[nt],
                                                                     acc[mt][nt], 0, 0, 0);
        __syncthreads();
    }

    // epilogue -> packed h2t; C/D: col=l&15 (=k within tile), row=(l>>4)*4+rg
    const int rblk0 = (bm0 >> 4) + wm * 4;
    const int cblk0 = (bn0 >> 4) + wn * 4;
#pragma unroll
    for (int nt = 0; nt < 4; ++nt) {
        const int col = bn0 + wn * 64 + nt * 16 + fr;
        const float bv = bias[col];
#pragma unroll
        for (int mt = 0; mt < 4; ++mt) {
            h4_t pk;
#pragma unroll
            for (int r = 0; r < 4; ++r) {
                float v = acc[mt][nt][r] + bv;
                pk[r] = (_Float16)fmaxf(v, NEG_SLOPE * v);
            }
            *reinterpret_cast<h4_t*>(
                &h2t[(((size_t)(cblk0 + nt) * 256 + rblk0 + mt) * 16 + fr) * 16 + fg * 4]) = pk;
        }
    }
}

// ---------------------------------------------------------------------------
// K4: fused additive chain, full-MFMA version.
// Grid (64 row-blocks x 8 r-chunks), 256 thr = 4 waves x 16 rows.
// Per r: stage {hval, w1f, w2f, wpf} (20KB, double-buffered, global_load_lds);
// phase A: 4x mfma 16x16x16; B: 8x mfma 16x16x32; C: 8x accumulating.
// Activations round-trip per-wave LDS in permuted-k layout; A-frags via
// ds_read_b64_tr_b16 (per-lane addr = base + l*8).
// ---------------------------------------------------------------------------
#define RCHUNK 8

__global__ __launch_bounds__(256) void fused_tail3(const _Float16* __restrict__ h2t,
                                                   const _Float16* __restrict__ wpack,
                                                   const float* __restrict__ a1b,
                                                   const float* __restrict__ a1bias,
                                                   const float* __restrict__ a2b,
                                                   const float* __restrict__ a2bias,
                                                   float* __restrict__ partials)
{
    __shared__ alignas(16) _Float16 stage[2][10240];  // 2 x 20KB
    __shared__ alignas(16) _Float16 aval[4][1024];    // per-wave a   (2KB)
    __shared__ alignas(16) _Float16 a2val[4][1024];   // per-wave a2  (2KB)

    const int tid = threadIdx.x;
    const int l = tid & 63, w = tid >> 6;
    const int c = l & 15, q = l >> 4;
    const int row0  = blockIdx.x * 64;
    const int rbase = blockIdx.y * RCHUNK;
    const float b1s = a1bias[0], b2s = a2bias[0];

    const unsigned trl    = l * 8;                 // per-lane tr-read offset (b64 slots)
    const unsigned abase  = lds_off(&aval[w][0]);
    const unsigned a2base = lds_off(&a2val[w][0]);

    auto STAGE = [&](int rl, int b) {
        const int r = rbase + rl;
        const _Float16* hsrc = h2t + ((size_t)r * 256 + blockIdx.x * 4) * 256;
        const _Float16* wsrc = wpack + (size_t)r * 9216;
#pragma unroll
        for (int i = 0; i < 5; ++i) {
            const int ch = w * 5 + i;
            const _Float16* src = (ch < 2) ? (hsrc + ch * 512) : (wsrc + (ch - 2) * 512);
            __builtin_amdgcn_global_load_lds(
                (const __attribute__((address_space(1))) void*)(src + l * 8),
                (__attribute__((address_space(3))) void*)&stage[b][ch * 512], 16, 0, 0);
        }
    };

    STAGE(0, 0);
    __syncthreads();

    f32x4 accT[4] = {};
    int cur = 0;

    for (int rl = 0; rl < RCHUNK; ++rl) {
        const int r = rbase + rl;
        if (rl + 1 < RCHUNK) STAGE(rl + 1, cur ^ 1);

        const _Float16* sp = &stage[cur][0];
        const unsigned sbytes = lds_off(sp);

        // ---- phase A: a = leaky(h_slice[16x16] @ W1r + a1b + bias1)
        h4_t ha = tr16(sbytes + w * 512 + trl);
        lgkm0();
        f32x4 pa[4];
#pragma unroll
        for (int nt = 0; nt < 4; ++nt) {
            h4_t bf = *reinterpret_cast<const h4_t*>(&sp[1024 + nt * 256 + l * 4]);
            pa[nt] = __builtin_amdgcn_mfma_f32_16x16x16f16(ha, bf, (f32x4){0.f,0.f,0.f,0.f}, 0, 0, 0);
        }
#pragma unroll
        for (int nt = 0; nt < 4; ++nt) {
            const float bb = a1b[r * 64 + nt * 16 + c] + b1s;
            h4_t pk;
#pragma unroll
            for (int rg = 0; rg < 4; ++rg) {
                float v = pa[nt][rg] + bb;
                pk[rg] = (_Float16)fmaxf(v, NEG_SLOPE * v);
            }
            const int kk = nt * 16 + c;
            const int hh = (kk >> 2) & 1;
            const int kp = (kk & 3) | ((kk >> 3) << 2);
            *reinterpret_cast<h4_t*>(&aval[w][hh * 512 + kp * 16 + q * 4]) = pk;
        }
        lgkm0();

        // ---- phase B: a2 = leaky(a @ W2r + a2b + bias2)
        h8_t afB[2];
#pragma unroll
        for (int kt = 0; kt < 2; ++kt) {
            h4_t lo = tr16(abase + kt * 512 + trl);
            h4_t hi = tr16(abase + 1024 + kt * 512 + trl);
            afB[kt] = __builtin_shufflevector(lo, hi, 0, 1, 2, 3, 4, 5, 6, 7);
        }
        lgkm0();
        f32x4 pb[4] = {};
#pragma unroll
        for (int kt = 0; kt < 2; ++kt)
#pragma unroll
            for (int nt = 0; nt < 4; ++nt) {
                h8_t bf = *reinterpret_cast<const h8_t*>(&sp[2048 + kt * 2048 + nt * 512 + l * 8]);
                pb[nt] = __builtin_amdgcn_mfma_f32_16x16x32_f16(afB[kt], bf, pb[nt], 0, 0, 0);
            }
#pragma unroll
        for (int nt = 0; nt < 4; ++nt) {
            const float bb = a2b[r * 64 + nt * 16 + c] + b2s;
            h4_t pk;
#pragma unroll
            for (int rg = 0; rg < 4; ++rg) {
                float v = pb[nt][rg] + bb;
                pk[rg] = (_Float16)fmaxf(v, NEG_SLOPE * v);
            }
            const int kk = nt * 16 + c;
            const int hh = (kk >> 2) & 1;
            const int kp = (kk & 3) | ((kk >> 3) << 2);
            *reinterpret_cast<h4_t*>(&a2val[w][hh * 512 + kp * 16 + q * 4]) = pk;
        }
        lgkm0();

        // ---- phase C: t2 += a2 @ WpR
        h8_t afC[2];
#pragma unroll
        for (int kt = 0; kt < 2; ++kt) {
            h4_t lo = tr16(a2base + kt * 512 + trl);
            h4_t hi = tr16(a2base + 1024 + kt * 512 + trl);
            afC[kt] = __builtin_shufflevector(lo, hi, 0, 1, 2, 3, 4, 5, 6, 7);
        }
        lgkm0();
#pragma unroll
        for (int kt = 0; kt < 2; ++kt)
#pragma unroll
            for (int nt = 0; nt < 4; ++nt) {
                h8_t bf = *reinterpret_cast<const h8_t*>(&sp[6144 + kt * 2048 + nt * 512 + l * 8]);
                accT[nt] = __builtin_amdgcn_mfma_f32_16x16x32_f16(afC[kt], bf, accT[nt], 0, 0, 0);
            }

        __syncthreads();   // drains vmcnt (next stage) + frees stage[cur]
        cur ^= 1;
    }

    // epilogue: partial t2 (C/D: col=c, rows q*4+rg)
#pragma unroll
    for (int nt = 0; nt < 4; ++nt)
#pragma unroll
        for (int rg = 0; rg < 4; ++rg)
            partials[((size_t)blockIdx.y * 4096 + row0 + w * 16 + q * 4 + rg) * 64 + nt * 16 + c] =
                accT[nt][rg];
}

// ---------------------------------------------------------------------------
// K5: reduce partials + bp2, dot with Wl, add bl -> out[4096]
// ---------------------------------------------------------------------------
__global__ __launch_bounds__(256) void reduce_out(const float* __restrict__ partials,
                                                  const float* __restrict__ bp2,
                                                  const float* __restrict__ Wl,
                                                  const float* __restrict__ bl,
                                                  float* __restrict__ out)
{
    const int tid = threadIdx.x;
    const int row = blockIdx.x * 4 + (tid >> 6);
    const int col = tid & 63;
    float s = bp2[col];
#pragma unroll
    for (int c = 0; c < RCHUNK; ++c)
        s += partials[(size_t)c * 4096 * 64 + (size_t)row * 64 + col];
    s *= Wl[col];
    s += __shfl_xor(s, 1);
    s += __shfl_xor(s, 2);
    s += __shfl_xor(s, 4);
    s += __shfl_xor(s, 8);
    s += __shfl_xor(s, 16);
    s += __shfl_xor(s, 32);
    if (col == 0) out[row] = s + bl[0];
}

// ---------------------------------------------------------------------------
extern "C" void kernel_launch(void* const* d_in, const int* in_sizes, int n_in,
                              void* d_out, int out_size, void* d_ws, size_t ws_size,
                              hipStream_t stream)
{
    const float* x      = (const float*)d_in[0];
    const float* Wpca   = (const float*)d_in[1];
    const float* bpca   = (const float*)d_in[2];
    const float* W1     = (const float*)d_in[3];
    const float* b1     = (const float*)d_in[4];
    const float* W2     = (const float*)d_in[5];
    const float* b2     = (const float*)d_in[6];
    const float* a1W    = (const float*)d_in[7];
    const float* a1b    = (const float*)d_in[8];
    const float* a1bias = (const float*)d_in[9];
    const float* a2W    = (const float*)d_in[10];
    const float* a2b    = (const float*)d_in[11];
    const float* a2bias = (const float*)d_in[12];
    const float* Wp2    = (const float*)d_in[13];
    const float* bp2    = (const float*)d_in[14];
    const float* Wl     = (const float*)d_in[15];
    const float* bl     = (const float*)d_in[16];
    float* out = (float*)d_out;

    // workspace layout (bytes)
    char* wsb = (char*)d_ws;
    float*    t        = (float*)   (wsb);                        // 1 MB
    _Float16* h1h      = (_Float16*)(wsb + (1ull  << 20));        // 8 MB
    _Float16* h2t      = (_Float16*)(wsb + (9ull  << 20));        // 8 MB
    _Float16* W2T      = (_Float16*)(wsb + (17ull << 20));        // 2 MB
    _Float16* wpack    = (_Float16*)(wsb + (19ull << 20));        // 1.2 MB
    float*    partials = (float*)   (wsb + (21ull << 20));        // 8 MB

    // independent prep
    transpose_f16<<<dim3(32, 32), 256, 0, stream>>>(W2, W2T);
    pack_tail_weights<<<dim3(2304), 256, 0, stream>>>(a1W, a2W, Wp2, wpack);
    // t = x @ W_pca + b_pca
    gemm_n64<<<dim3(1, 128), 256, 0, stream>>>(x, Wpca, bpca, t, 1024);
    // h1 = leaky(t @ W1 + b1) -> fp16
    gemm_n1024_f16out<<<dim3(8, 32), 256, 0, stream>>>(t, W1, b1, h1h, 64);
    // h2 (packed) = leaky(h1 @ W2 + b2) via MFMA
    gemm_mfma_f16<<<dim3(8, 32), 256, 0, stream>>>(h1h, W2T, b2, h2t);
    // fused additive chain (MFMA) -> partial t2 per r-chunk
    fused_tail3<<<dim3(64, 8), 256, 0, stream>>>(h2t, wpack, a1b, a1bias,
                                                 a2b, a2bias, partials);
    // reduce partials + PCA2 bias + last layer
    reduce_out<<<dim3(1024), 256, 0, stream>>>(partials, bp2, Wl, bl, out);
}

// Round 7
// 87.256 us; speedup vs baseline: 5.4785x; 1.2833x over previous
//
#include <hip/hip_runtime.h>

#define NEG_SLOPE 0.1f

__device__ __forceinline__ float leaky(float v) { return v > 0.0f ? v : NEG_SLOPE * v; }

typedef _Float16 h4_t __attribute__((ext_vector_type(4)));
typedef _Float16 h8_t __attribute__((ext_vector_type(8)));
typedef float f32x4 __attribute__((ext_vector_type(4)));

__device__ __forceinline__ unsigned lds_off(const void* p) {
    return (unsigned)(unsigned long long)p;   // low 32 bits of generic LDS ptr = DS offset
}

__device__ __forceinline__ void lgkm0() {
    asm volatile("s_waitcnt lgkmcnt(0)" ::: "memory");
    __builtin_amdgcn_sched_barrier(0);        // rule #18: keep MFMA below the wait
}

__device__ __forceinline__ h4_t tr16(unsigned addr) {
    h4_t d;
    asm volatile("ds_read_b64_tr_b16 %0, %1" : "=v"(d) : "v"(addr) : "memory");
    return d;
}

// ---------------------------------------------------------------------------
// K1: split-K fp32 GEMM for t = x @ W_pca.
// Grid (128 row-blocks of 32, 8 k-chunks of 128). Partials [8][4096][64].
// ---------------------------------------------------------------------------
__global__ __launch_bounds__(256) void gemm_n64_splitk(const float* __restrict__ A,
                                                       const float* __restrict__ B,
                                                       float* __restrict__ P)
{
    __shared__ alignas(16) float As[32][33];   // [k][m], padded
    __shared__ alignas(16) float Bs[32][64];
    const int tid   = threadIdx.x;
    const int row0  = blockIdx.x * 32;
    const int kbase = blockIdx.y * 128;
    const int r0    = (tid >> 4) * 2;
    const int c0    = (tid & 15) * 4;
    const int am    = tid >> 3;
    const int ak    = (tid & 7) * 4;
    float acc[2][4] = {};

#pragma unroll
    for (int kc = 0; kc < 128; kc += 32) {
        const int k0 = kbase + kc;
        float4 va = *reinterpret_cast<const float4*>(&A[(size_t)(row0 + am) * 1024 + k0 + ak]);
        As[ak + 0][am] = va.x; As[ak + 1][am] = va.y;
        As[ak + 2][am] = va.z; As[ak + 3][am] = va.w;
#pragma unroll
        for (int p = 0; p < 2; ++p) {
            int idx = tid + p * 256;
            int kk  = idx >> 4;
            int nq  = (idx & 15) * 4;
            *reinterpret_cast<float4*>(&Bs[kk][nq]) =
                *reinterpret_cast<const float4*>(&B[(size_t)(k0 + kk) * 64 + nq]);
        }
        __syncthreads();
#pragma unroll
        for (int k = 0; k < 32; ++k) {
            float a0 = As[k][r0], a1 = As[k][r0 + 1];
            float4 bv = *reinterpret_cast<const float4*>(&Bs[k][c0]);
            acc[0][0] = fmaf(a0, bv.x, acc[0][0]); acc[0][1] = fmaf(a0, bv.y, acc[0][1]);
            acc[0][2] = fmaf(a0, bv.z, acc[0][2]); acc[0][3] = fmaf(a0, bv.w, acc[0][3]);
            acc[1][0] = fmaf(a1, bv.x, acc[1][0]); acc[1][1] = fmaf(a1, bv.y, acc[1][1]);
            acc[1][2] = fmaf(a1, bv.z, acc[1][2]); acc[1][3] = fmaf(a1, bv.w, acc[1][3]);
        }
        __syncthreads();
    }
#pragma unroll
    for (int i = 0; i < 2; ++i) {
        float4 o; o.x = acc[i][0]; o.y = acc[i][1]; o.z = acc[i][2]; o.w = acc[i][3];
        *reinterpret_cast<float4*>(
            &P[((size_t)blockIdx.y * 4096 + row0 + r0 + i) * 64 + c0]) = o;
    }
}

// K1b: t = sum_c P[c] + bias   (262144 elems)
__global__ __launch_bounds__(256) void combine_t(const float* __restrict__ P,
                                                 const float* __restrict__ bias,
                                                 float* __restrict__ t)
{
    const int idx = blockIdx.x * 256 + threadIdx.x;
    float s = bias[idx & 63];
#pragma unroll
    for (int c = 0; c < 8; ++c)
        s += P[(size_t)c * 262144 + idx];
    t[idx] = s;
}

// ---------------------------------------------------------------------------
// K2: h1[M,1024] = leaky(t[M,64] @ W1 + b1)  -> fp16
// ---------------------------------------------------------------------------
__global__ __launch_bounds__(256) void gemm_n1024_f16out(const float* __restrict__ A,
                                                         const float* __restrict__ B,
                                                         const float* __restrict__ bias,
                                                         _Float16* __restrict__ C, int K)
{
    __shared__ alignas(16) float As[32][132];
    __shared__ alignas(16) float Bs[32][128];
    const int tid  = threadIdx.x;
    const int row0 = blockIdx.y * 128;
    const int col0 = blockIdx.x * 128;
    const int tm0  = (tid >> 4) * 4;
    const int tn0  = (tid & 15) * 4;
    float acc[2][2][4][4] = {};
    float4 pa[4], pb[4];

    auto load_regs = [&](int k0) {
#pragma unroll
        for (int p = 0; p < 4; ++p) {
            int idx = tid + p * 256;
            int m   = idx >> 3;
            int kq  = (idx & 7) * 4;
            pa[p] = *reinterpret_cast<const float4*>(&A[(size_t)(row0 + m) * K + k0 + kq]);
            int kk = idx >> 5;
            int nq = (idx & 31) * 4;
            pb[p] = *reinterpret_cast<const float4*>(&B[(size_t)(k0 + kk) * 1024 + col0 + nq]);
        }
    };

    load_regs(0);
    for (int k0 = 0; k0 < K; k0 += 32) {
#pragma unroll
        for (int p = 0; p < 4; ++p) {
            int idx = tid + p * 256;
            int m   = idx >> 3;
            int kq  = (idx & 7) * 4;
            As[kq + 0][m] = pa[p].x; As[kq + 1][m] = pa[p].y;
            As[kq + 2][m] = pa[p].z; As[kq + 3][m] = pa[p].w;
            int kk = idx >> 5;
            int nq = (idx & 31) * 4;
            *reinterpret_cast<float4*>(&Bs[kk][nq]) = pb[p];
        }
        __syncthreads();
        if (k0 + 32 < K) load_regs(k0 + 32);
#pragma unroll
        for (int k = 0; k < 32; ++k) {
            float a[2][4], b[2][4];
            *reinterpret_cast<float4*>(a[0]) = *reinterpret_cast<const float4*>(&As[k][tm0]);
            *reinterpret_cast<float4*>(a[1]) = *reinterpret_cast<const float4*>(&As[k][64 + tm0]);
            *reinterpret_cast<float4*>(b[0]) = *reinterpret_cast<const float4*>(&Bs[k][tn0]);
            *reinterpret_cast<float4*>(b[1]) = *reinterpret_cast<const float4*>(&Bs[k][64 + tn0]);
#pragma unroll
            for (int bi = 0; bi < 2; ++bi)
#pragma unroll
                for (int bj = 0; bj < 2; ++bj)
#pragma unroll
                    for (int i = 0; i < 4; ++i)
#pragma unroll
                        for (int j = 0; j < 4; ++j)
                            acc[bi][bj][i][j] = fmaf(a[bi][i], b[bj][j], acc[bi][bj][i][j]);
        }
        __syncthreads();
    }
#pragma unroll
    for (int bi = 0; bi < 2; ++bi)
#pragma unroll
        for (int i = 0; i < 4; ++i) {
            int rr = row0 + bi * 64 + tm0 + i;
#pragma unroll
            for (int bj = 0; bj < 2; ++bj) {
                int cc = col0 + bj * 64 + tn0;
                h4_t o;
                o[0] = (_Float16)leaky(acc[bi][bj][i][0] + bias[cc + 0]);
                o[1] = (_Float16)leaky(acc[bi][bj][i][1] + bias[cc + 1]);
                o[2] = (_Float16)leaky(acc[bi][bj][i][2] + bias[cc + 2]);
                o[3] = (_Float16)leaky(acc[bi][bj][i][3] + bias[cc + 3]);
                *reinterpret_cast<h4_t*>(&C[(size_t)rr * 1024 + cc]) = o;
            }
        }
}

// ---------------------------------------------------------------------------
// K2b: W2T[n][k] = (fp16) W2[k][n]
// ---------------------------------------------------------------------------
__global__ __launch_bounds__(256) void transpose_f16(const float* __restrict__ W,
                                                     _Float16* __restrict__ WT)
{
    __shared__ float tile[32][33];
    const int tid = threadIdx.x;
    const int k0  = blockIdx.y * 32;
    const int n0  = blockIdx.x * 32;
    const int r   = tid >> 3;
    const int c   = (tid & 7) * 4;
    float4 v = *reinterpret_cast<const float4*>(&W[(size_t)(k0 + r) * 1024 + n0 + c]);
    tile[r][c + 0] = v.x; tile[r][c + 1] = v.y; tile[r][c + 2] = v.z; tile[r][c + 3] = v.w;
    __syncthreads();
    h4_t o;
    o[0] = (_Float16)tile[c + 0][r];
    o[1] = (_Float16)tile[c + 1][r];
    o[2] = (_Float16)tile[c + 2][r];
    o[3] = (_Float16)tile[c + 3][r];
    *reinterpret_cast<h4_t*>(&WT[(size_t)(n0 + r) * 1024 + k0 + c]) = o;
}

// ---------------------------------------------------------------------------
// K2c: pack tail weights into MFMA B-fragment order, fp16.
// ---------------------------------------------------------------------------
__global__ __launch_bounds__(256) void pack_tail_weights(const float* __restrict__ a1W,
                                                         const float* __restrict__ a2W,
                                                         const float* __restrict__ Wp2,
                                                         _Float16* __restrict__ wpack)
{
    const int tid = blockIdx.x * 256 + threadIdx.x;   // < 589824
    const int r = tid / 9216, qq = tid % 9216;
    float v;
    if (qq < 1024) {
        int nt = qq >> 8, rem = qq & 255, l = rem >> 2, j = rem & 3;
        int n = nt * 16 + (l & 15), k = (l >> 4) * 4 + j;
        v = a1W[(size_t)r * 1024 + k * 64 + n];
    } else if (qq < 5120) {
        int p = qq - 1024, kt = p >> 11, u = p & 2047, nt = u >> 9, s = u & 511, l = s >> 3, j = s & 7;
        int n = nt * 16 + (l & 15), k = kt * 32 + (l >> 4) * 8 + j;
        v = a2W[(size_t)r * 4096 + k * 64 + n];
    } else {
        int p = qq - 5120, kt = p >> 11, u = p & 2047, nt = u >> 9, s = u & 511, l = s >> 3, j = s & 7;
        int n = nt * 16 + (l & 15), k = kt * 32 + (l >> 4) * 8 + j;
        v = Wp2[((size_t)r * 64 + k) * 64 + n];
    }
    wpack[tid] = (_Float16)v;
}

// ---------------------------------------------------------------------------
// K3: h2 = leaky(h1 @ W2 + b2) via fp16 MFMA; output PACKED h2t.
// ---------------------------------------------------------------------------
__global__ __launch_bounds__(256) void gemm_mfma_f16(const _Float16* __restrict__ A,
                                                     const _Float16* __restrict__ BT,
                                                     const float* __restrict__ bias,
                                                     _Float16* __restrict__ h2t)
{
    __shared__ alignas(16) _Float16 As[128 * 32];
    __shared__ alignas(16) _Float16 Bs[128 * 32];
    const int tid = threadIdx.x;
    const int l   = tid & 63;
    const int w   = tid >> 6;
    const int wm  = w >> 1;
    const int wn  = w & 1;
    const int bm0 = blockIdx.y * 128;
    const int bn0 = blockIdx.x * 128;
    const int fr  = l & 15;
    const int fg  = l >> 4;
    const int srow  = l >> 2;
    const int sslot = l & 3;

    f32x4 acc[4][4] = {};

    for (int k0 = 0; k0 < 1024; k0 += 32) {
#pragma unroll
        for (int i = 0; i < 2; ++i) {
            const int r0   = (w * 2 + i) * 16;
            const int rowA = r0 + srow;
            const int slot = sslot ^ (rowA & 3);
            const _Float16* ga = &A[(size_t)(bm0 + rowA) * 1024 + k0 + slot * 8];
            __builtin_amdgcn_global_load_lds(
                (const __attribute__((address_space(1))) void*)ga,
                (__attribute__((address_space(3))) void*)&As[r0 * 32], 16, 0, 0);
            const _Float16* gb = &BT[(size_t)(bn0 + rowA) * 1024 + k0 + slot * 8];
            __builtin_amdgcn_global_load_lds(
                (const __attribute__((address_space(1))) void*)gb,
                (__attribute__((address_space(3))) void*)&Bs[r0 * 32], 16, 0, 0);
        }
        __syncthreads();

        h8_t af[4], bf[4];
#pragma unroll
        for (int mt = 0; mt < 4; ++mt) {
            int row = wm * 64 + mt * 16 + fr;
            af[mt] = *reinterpret_cast<const h8_t*>(&As[row * 32 + ((fg ^ (row & 3)) << 3)]);
        }
#pragma unroll
        for (int nt = 0; nt < 4; ++nt) {
            int row = wn * 64 + nt * 16 + fr;
            bf[nt] = *reinterpret_cast<const h8_t*>(&Bs[row * 32 + ((fg ^ (row & 3)) << 3)]);
        }
#pragma unroll
        for (int mt = 0; mt < 4; ++mt)
#pragma unroll
            for (int nt = 0; nt < 4; ++nt)
                acc[mt][nt] = __builtin_amdgcn_mfma_f32_16x16x32_f16(af[mt], bf[nt],
                                                                     acc[mt][nt], 0, 0, 0);
        __syncthreads();
    }

    const int rblk0 = (bm0 >> 4) + wm * 4;
    const int cblk0 = (bn0 >> 4) + wn * 4;
#pragma unroll
    for (int nt = 0; nt < 4; ++nt) {
        const int col = bn0 + wn * 64 + nt * 16 + fr;
        const float bv = bias[col];
#pragma unroll
        for (int mt = 0; mt < 4; ++mt) {
            h4_t pk;
#pragma unroll
            for (int r = 0; r < 4; ++r) {
                float v = acc[mt][nt][r] + bv;
                pk[r] = (_Float16)fmaxf(v, NEG_SLOPE * v);
            }
            *reinterpret_cast<h4_t*>(
                &h2t[(((size_t)(cblk0 + nt) * 256 + rblk0 + mt) * 16 + fr) * 16 + fg * 4]) = pk;
        }
    }
}

// ---------------------------------------------------------------------------
// K4: fused additive chain, full-MFMA (unchanged from round 5)
// ---------------------------------------------------------------------------
#define RCHUNK 8

__global__ __launch_bounds__(256) void fused_tail3(const _Float16* __restrict__ h2t,
                                                   const _Float16* __restrict__ wpack,
                                                   const float* __restrict__ a1b,
                                                   const float* __restrict__ a1bias,
                                                   const float* __restrict__ a2b,
                                                   const float* __restrict__ a2bias,
                                                   float* __restrict__ partials)
{
    __shared__ alignas(16) _Float16 stage[2][10240];  // 2 x 20KB
    __shared__ alignas(16) _Float16 aval[4][1024];
    __shared__ alignas(16) _Float16 a2val[4][1024];

    const int tid = threadIdx.x;
    const int l = tid & 63, w = tid >> 6;
    const int c = l & 15, q = l >> 4;
    const int row0  = blockIdx.x * 64;
    const int rbase = blockIdx.y * RCHUNK;
    const float b1s = a1bias[0], b2s = a2bias[0];

    const unsigned trl    = l * 8;
    const unsigned abase  = lds_off(&aval[w][0]);
    const unsigned a2base = lds_off(&a2val[w][0]);

    auto STAGE = [&](int rl, int b) {
        const int r = rbase + rl;
        const _Float16* hsrc = h2t + ((size_t)r * 256 + blockIdx.x * 4) * 256;
        const _Float16* wsrc = wpack + (size_t)r * 9216;
#pragma unroll
        for (int i = 0; i < 5; ++i) {
            const int ch = w * 5 + i;
            const _Float16* src = (ch < 2) ? (hsrc + ch * 512) : (wsrc + (ch - 2) * 512);
            __builtin_amdgcn_global_load_lds(
                (const __attribute__((address_space(1))) void*)(src + l * 8),
                (__attribute__((address_space(3))) void*)&stage[b][ch * 512], 16, 0, 0);
        }
    };

    STAGE(0, 0);
    __syncthreads();

    f32x4 accT[4] = {};
    int cur = 0;

    for (int rl = 0; rl < RCHUNK; ++rl) {
        const int r = rbase + rl;
        if (rl + 1 < RCHUNK) STAGE(rl + 1, cur ^ 1);

        const _Float16* sp = &stage[cur][0];
        const unsigned sbytes = lds_off(sp);

        // ---- phase A
        h4_t ha = tr16(sbytes + w * 512 + trl);
        lgkm0();
        f32x4 pa[4];
#pragma unroll
        for (int nt = 0; nt < 4; ++nt) {
            h4_t bf = *reinterpret_cast<const h4_t*>(&sp[1024 + nt * 256 + l * 4]);
            pa[nt] = __builtin_amdgcn_mfma_f32_16x16x16f16(ha, bf, (f32x4){0.f,0.f,0.f,0.f}, 0, 0, 0);
        }
#pragma unroll
        for (int nt = 0; nt < 4; ++nt) {
            const float bb = a1b[r * 64 + nt * 16 + c] + b1s;
            h4_t pk;
#pragma unroll
            for (int rg = 0; rg < 4; ++rg) {
                float v = pa[nt][rg] + bb;
                pk[rg] = (_Float16)fmaxf(v, NEG_SLOPE * v);
            }
            const int kk = nt * 16 + c;
            const int hh = (kk >> 2) & 1;
            const int kp = (kk & 3) | ((kk >> 3) << 2);
            *reinterpret_cast<h4_t*>(&aval[w][hh * 512 + kp * 16 + q * 4]) = pk;
        }
        lgkm0();

        // ---- phase B
        h8_t afB[2];
#pragma unroll
        for (int kt = 0; kt < 2; ++kt) {
            h4_t lo = tr16(abase + kt * 512 + trl);
            h4_t hi = tr16(abase + 1024 + kt * 512 + trl);
            afB[kt] = __builtin_shufflevector(lo, hi, 0, 1, 2, 3, 4, 5, 6, 7);
        }
        lgkm0();
        f32x4 pb[4] = {};
#pragma unroll
        for (int kt = 0; kt < 2; ++kt)
#pragma unroll
            for (int nt = 0; nt < 4; ++nt) {
                h8_t bf = *reinterpret_cast<const h8_t*>(&sp[2048 + kt * 2048 + nt * 512 + l * 8]);
                pb[nt] = __builtin_amdgcn_mfma_f32_16x16x32_f16(afB[kt], bf, pb[nt], 0, 0, 0);
            }
#pragma unroll
        for (int nt = 0; nt < 4; ++nt) {
            const float bb = a2b[r * 64 + nt * 16 + c] + b2s;
            h4_t pk;
#pragma unroll
            for (int rg = 0; rg < 4; ++rg) {
                float v = pb[nt][rg] + bb;
                pk[rg] = (_Float16)fmaxf(v, NEG_SLOPE * v);
            }
            const int kk = nt * 16 + c;
            const int hh = (kk >> 2) & 1;
            const int kp = (kk & 3) | ((kk >> 3) << 2);
            *reinterpret_cast<h4_t*>(&a2val[w][hh * 512 + kp * 16 + q * 4]) = pk;
        }
        lgkm0();

        // ---- phase C
        h8_t afC[2];
#pragma unroll
        for (int kt = 0; kt < 2; ++kt) {
            h4_t lo = tr16(a2base + kt * 512 + trl);
            h4_t hi = tr16(a2base + 1024 + kt * 512 + trl);
            afC[kt] = __builtin_shufflevector(lo, hi, 0, 1, 2, 3, 4, 5, 6, 7);
        }
        lgkm0();
#pragma unroll
        for (int kt = 0; kt < 2; ++kt)
#pragma unroll
            for (int nt = 0; nt < 4; ++nt) {
                h8_t bf = *reinterpret_cast<const h8_t*>(&sp[6144 + kt * 2048 + nt * 512 + l * 8]);
                accT[nt] = __builtin_amdgcn_mfma_f32_16x16x32_f16(afC[kt], bf, accT[nt], 0, 0, 0);
            }

        __syncthreads();
        cur ^= 1;
    }

#pragma unroll
    for (int nt = 0; nt < 4; ++nt)
#pragma unroll
        for (int rg = 0; rg < 4; ++rg)
            partials[((size_t)blockIdx.y * 4096 + row0 + w * 16 + q * 4 + rg) * 64 + nt * 16 + c] =
                accT[nt][rg];
}

// ---------------------------------------------------------------------------
// K5: reduce partials + bp2, dot with Wl, add bl -> out[4096]
// ---------------------------------------------------------------------------
__global__ __launch_bounds__(256) void reduce_out(const float* __restrict__ partials,
                                                  const float* __restrict__ bp2,
                                                  const float* __restrict__ Wl,
                                                  const float* __restrict__ bl,
                                                  float* __restrict__ out)
{
    const int tid = threadIdx.x;
    const int row = blockIdx.x * 4 + (tid >> 6);
    const int col = tid & 63;
    float s = bp2[col];
#pragma unroll
    for (int c = 0; c < RCHUNK; ++c)
        s += partials[(size_t)c * 4096 * 64 + (size_t)row * 64 + col];
    s *= Wl[col];
    s += __shfl_xor(s, 1);
    s += __shfl_xor(s, 2);
    s += __shfl_xor(s, 4);
    s += __shfl_xor(s, 8);
    s += __shfl_xor(s, 16);
    s += __shfl_xor(s, 32);
    if (col == 0) out[row] = s + bl[0];
}

// ---------------------------------------------------------------------------
extern "C" void kernel_launch(void* const* d_in, const int* in_sizes, int n_in,
                              void* d_out, int out_size, void* d_ws, size_t ws_size,
                              hipStream_t stream)
{
    const float* x      = (const float*)d_in[0];
    const float* Wpca   = (const float*)d_in[1];
    const float* bpca   = (const float*)d_in[2];
    const float* W1     = (const float*)d_in[3];
    const float* b1     = (const float*)d_in[4];
    const float* W2     = (const float*)d_in[5];
    const float* b2     = (const float*)d_in[6];
    const float* a1W    = (const float*)d_in[7];
    const float* a1b    = (const float*)d_in[8];
    const float* a1bias = (const float*)d_in[9];
    const float* a2W    = (const float*)d_in[10];
    const float* a2b    = (const float*)d_in[11];
    const float* a2bias = (const float*)d_in[12];
    const float* Wp2    = (const float*)d_in[13];
    const float* bp2    = (const float*)d_in[14];
    const float* Wl     = (const float*)d_in[15];
    const float* bl     = (const float*)d_in[16];
    float* out = (float*)d_out;

    // workspace layout (bytes)
    char* wsb = (char*)d_ws;
    float*    t        = (float*)   (wsb);                        // 1 MB
    _Float16* h1h      = (_Float16*)(wsb + (1ull  << 20));        // 8 MB
    _Float16* h2t      = (_Float16*)(wsb + (9ull  << 20));        // 8 MB
    _Float16* W2T      = (_Float16*)(wsb + (17ull << 20));        // 2 MB
    _Float16* wpack    = (_Float16*)(wsb + (19ull << 20));        // 1.2 MB
    float*    partials = (float*)   (wsb + (21ull << 20));        // 8 MB
    float*    tpart    = (float*)   (wsb + (9ull  << 20));        // 8 MB, aliases h2t
                                                                  // (dead before K3 writes h2t)

    // independent prep
    transpose_f16<<<dim3(32, 32), 256, 0, stream>>>(W2, W2T);
    pack_tail_weights<<<dim3(2304), 256, 0, stream>>>(a1W, a2W, Wp2, wpack);
    // t = x @ W_pca + b_pca   (split-K fp32: 1024 WGs, then combine)
    gemm_n64_splitk<<<dim3(128, 8), 256, 0, stream>>>(x, Wpca, tpart);
    combine_t<<<dim3(1024), 256, 0, stream>>>(tpart, bpca, t);
    // h1 = leaky(t @ W1 + b1) -> fp16
    gemm_n1024_f16out<<<dim3(8, 32), 256, 0, stream>>>(t, W1, b1, h1h, 64);
    // h2 (packed) = leaky(h1 @ W2 + b2) via MFMA
    gemm_mfma_f16<<<dim3(8, 32), 256, 0, stream>>>(h1h, W2T, b2, h2t);
    // fused additive chain (MFMA) -> partial t2 per r-chunk
    fused_tail3<<<dim3(64, 8), 256, 0, stream>>>(h2t, wpack, a1b, a1bias,
                                                 a2b, a2bias, partials);
    // reduce partials + PCA2 bias + last layer
    reduce_out<<<dim3(1024), 256, 0, stream>>>(partials, bp2, Wl, bl, out);
}

// Round 9
// 82.521 us; speedup vs baseline: 5.7928x; 1.0574x over previous
//
#include <hip/hip_runtime.h>

#define NEG_SLOPE 0.1f

__device__ __forceinline__ float leaky(float v) { return v > 0.0f ? v : NEG_SLOPE * v; }

typedef _Float16 h4_t __attribute__((ext_vector_type(4)));
typedef _Float16 h8_t __attribute__((ext_vector_type(8)));
typedef float f32x4 __attribute__((ext_vector_type(4)));

__device__ __forceinline__ unsigned lds_off(const void* p) {
    return (unsigned)(unsigned long long)p;
}

__device__ __forceinline__ void lgkm0() {
    asm volatile("s_waitcnt lgkmcnt(0)" ::: "memory");
    __builtin_amdgcn_sched_barrier(0);        // rule #18
}

__device__ __forceinline__ h4_t tr16(unsigned addr) {
    h4_t d;
    asm volatile("ds_read_b64_tr_b16 %0, %1" : "=v"(d) : "v"(addr) : "memory");
    return d;
}

// ---------------------------------------------------------------------------
// PREP: W2T (fp16) + tail-weight packing in one launch.
// blocks [0,1024): W2T tiles; [1024,3328): pack. (W1T branch removed — K2
// reverted to fp32 this round; bisecting round-8's failure.)
// ---------------------------------------------------------------------------
__global__ __launch_bounds__(256) void prep_weights(const float* __restrict__ W2,
                                                    const float* __restrict__ a1W,
                                                    const float* __restrict__ a2W,
                                                    const float* __restrict__ Wp2,
                                                    _Float16* __restrict__ W2T,
                                                    _Float16* __restrict__ wpack)
{
    __shared__ float tile[32][33];
    const int b   = blockIdx.x;
    const int tid = threadIdx.x;

    if (b < 1024) {                         // W2T[n][k] = fp16 W2[k][n]
        const int n0 = (b & 31) * 32, k0 = (b >> 5) * 32;
        const int r = tid >> 3, c4 = (tid & 7) * 4;
        float4 v = *reinterpret_cast<const float4*>(&W2[(size_t)(k0 + r) * 1024 + n0 + c4]);
        tile[r][c4 + 0] = v.x; tile[r][c4 + 1] = v.y;
        tile[r][c4 + 2] = v.z; tile[r][c4 + 3] = v.w;
        __syncthreads();
        h4_t o;
        o[0] = (_Float16)tile[c4 + 0][r]; o[1] = (_Float16)tile[c4 + 1][r];
        o[2] = (_Float16)tile[c4 + 2][r]; o[3] = (_Float16)tile[c4 + 3][r];
        *reinterpret_cast<h4_t*>(&W2T[(size_t)(n0 + r) * 1024 + k0 + c4]) = o;
    } else {                                // pack tail weights (MFMA B-frag order)
        const int idx = (b - 1024) * 256 + tid;   // < 589824
        if (idx < 589824) {
            const int r = idx / 9216, qq = idx % 9216;
            float v;
            if (qq < 1024) {
                int nt = qq >> 8, rem = qq & 255, l = rem >> 2, j = rem & 3;
                int n = nt * 16 + (l & 15), k = (l >> 4) * 4 + j;
                v = a1W[(size_t)r * 1024 + k * 64 + n];
            } else if (qq < 5120) {
                int p = qq - 1024, kt = p >> 11, u = p & 2047, nt = u >> 9, s = u & 511,
                    l = s >> 3, j = s & 7;
                int n = nt * 16 + (l & 15), k = kt * 32 + (l >> 4) * 8 + j;
                v = a2W[(size_t)r * 4096 + k * 64 + n];
            } else {
                int p = qq - 5120, kt = p >> 11, u = p & 2047, nt = u >> 9, s = u & 511,
                    l = s >> 3, j = s & 7;
                int n = nt * 16 + (l & 15), k = kt * 32 + (l >> 4) * 8 + j;
                v = Wp2[((size_t)r * 64 + k) * 64 + n];
            }
            wpack[idx] = (_Float16)v;
        }
    }
}

// ---------------------------------------------------------------------------
// K1: split-K fp32 GEMM for t = x @ W_pca. Partials [8][4096][64].
// ---------------------------------------------------------------------------
__global__ __launch_bounds__(256) void gemm_n64_splitk(const float* __restrict__ A,
                                                       const float* __restrict__ B,
                                                       float* __restrict__ P)
{
    __shared__ alignas(16) float As[32][33];
    __shared__ alignas(16) float Bs[32][64];
    const int tid   = threadIdx.x;
    const int row0  = blockIdx.x * 32;
    const int kbase = blockIdx.y * 128;
    const int r0    = (tid >> 4) * 2;
    const int c0    = (tid & 15) * 4;
    const int am    = tid >> 3;
    const int ak    = (tid & 7) * 4;
    float acc[2][4] = {};

#pragma unroll
    for (int kc = 0; kc < 128; kc += 32) {
        const int k0 = kbase + kc;
        float4 va = *reinterpret_cast<const float4*>(&A[(size_t)(row0 + am) * 1024 + k0 + ak]);
        As[ak + 0][am] = va.x; As[ak + 1][am] = va.y;
        As[ak + 2][am] = va.z; As[ak + 3][am] = va.w;
#pragma unroll
        for (int p = 0; p < 2; ++p) {
            int idx = tid + p * 256;
            int kk  = idx >> 4;
            int nq  = (idx & 15) * 4;
            *reinterpret_cast<float4*>(&Bs[kk][nq]) =
                *reinterpret_cast<const float4*>(&B[(size_t)(k0 + kk) * 64 + nq]);
        }
        __syncthreads();
#pragma unroll
        for (int k = 0; k < 32; ++k) {
            float a0 = As[k][r0], a1 = As[k][r0 + 1];
            float4 bv = *reinterpret_cast<const float4*>(&Bs[k][c0]);
            acc[0][0] = fmaf(a0, bv.x, acc[0][0]); acc[0][1] = fmaf(a0, bv.y, acc[0][1]);
            acc[0][2] = fmaf(a0, bv.z, acc[0][2]); acc[0][3] = fmaf(a0, bv.w, acc[0][3]);
            acc[1][0] = fmaf(a1, bv.x, acc[1][0]); acc[1][1] = fmaf(a1, bv.y, acc[1][1]);
            acc[1][2] = fmaf(a1, bv.z, acc[1][2]); acc[1][3] = fmaf(a1, bv.w, acc[1][3]);
        }
        __syncthreads();
    }
#pragma unroll
    for (int i = 0; i < 2; ++i) {
        float4 o; o.x = acc[i][0]; o.y = acc[i][1]; o.z = acc[i][2]; o.w = acc[i][3];
        *reinterpret_cast<float4*>(
            &P[((size_t)blockIdx.y * 4096 + row0 + r0 + i) * 64 + c0]) = o;
    }
}

// K1b: t = sum_c P[c] + bias (f32)
__global__ __launch_bounds__(256) void combine_t(const float* __restrict__ P,
                                                 const float* __restrict__ bias,
                                                 float* __restrict__ t)
{
    const int idx = blockIdx.x * 256 + threadIdx.x;
    float s = bias[idx & 63];
#pragma unroll
    for (int c = 0; c < 8; ++c)
        s += P[(size_t)c * 262144 + idx];
    t[idx] = s;
}

// ---------------------------------------------------------------------------
// K2: h1[M,1024] = leaky(t[M,64] @ W1 + b1) -> fp16   (round-7 proven fp32)
// ---------------------------------------------------------------------------
__global__ __launch_bounds__(256) void gemm_n1024_f16out(const float* __restrict__ A,
                                                         const float* __restrict__ B,
                                                         const float* __restrict__ bias,
                                                         _Float16* __restrict__ C, int K)
{
    __shared__ alignas(16) float As[32][132];
    __shared__ alignas(16) float Bs[32][128];
    const int tid  = threadIdx.x;
    const int row0 = blockIdx.y * 128;
    const int col0 = blockIdx.x * 128;
    const int tm0  = (tid >> 4) * 4;
    const int tn0  = (tid & 15) * 4;
    float acc[2][2][4][4] = {};
    float4 pa[4], pb[4];

    auto load_regs = [&](int k0) {
#pragma unroll
        for (int p = 0; p < 4; ++p) {
            int idx = tid + p * 256;
            int m   = idx >> 3;
            int kq  = (idx & 7) * 4;
            pa[p] = *reinterpret_cast<const float4*>(&A[(size_t)(row0 + m) * K + k0 + kq]);
            int kk = idx >> 5;
            int nq = (idx & 31) * 4;
            pb[p] = *reinterpret_cast<const float4*>(&B[(size_t)(k0 + kk) * 1024 + col0 + nq]);
        }
    };

    load_regs(0);
    for (int k0 = 0; k0 < K; k0 += 32) {
#pragma unroll
        for (int p = 0; p < 4; ++p) {
            int idx = tid + p * 256;
            int m   = idx >> 3;
            int kq  = (idx & 7) * 4;
            As[kq + 0][m] = pa[p].x; As[kq + 1][m] = pa[p].y;
            As[kq + 2][m] = pa[p].z; As[kq + 3][m] = pa[p].w;
            int kk = idx >> 5;
            int nq = (idx & 31) * 4;
            *reinterpret_cast<float4*>(&Bs[kk][nq]) = pb[p];
        }
        __syncthreads();
        if (k0 + 32 < K) load_regs(k0 + 32);
#pragma unroll
        for (int k = 0; k < 32; ++k) {
            float a[2][4], b[2][4];
            *reinterpret_cast<float4*>(a[0]) = *reinterpret_cast<const float4*>(&As[k][tm0]);
            *reinterpret_cast<float4*>(a[1]) = *reinterpret_cast<const float4*>(&As[k][64 + tm0]);
            *reinterpret_cast<float4*>(b[0]) = *reinterpret_cast<const float4*>(&Bs[k][tn0]);
            *reinterpret_cast<float4*>(b[1]) = *reinterpret_cast<const float4*>(&Bs[k][64 + tn0]);
#pragma unroll
            for (int bi = 0; bi < 2; ++bi)
#pragma unroll
                for (int bj = 0; bj < 2; ++bj)
#pragma unroll
                    for (int i = 0; i < 4; ++i)
#pragma unroll
                        for (int j = 0; j < 4; ++j)
                            acc[bi][bj][i][j] = fmaf(a[bi][i], b[bj][j], acc[bi][bj][i][j]);
        }
        __syncthreads();
    }
#pragma unroll
    for (int bi = 0; bi < 2; ++bi)
#pragma unroll
        for (int i = 0; i < 4; ++i) {
            int rr = row0 + bi * 64 + tm0 + i;
#pragma unroll
            for (int bj = 0; bj < 2; ++bj) {
                int cc = col0 + bj * 64 + tn0;
                h4_t o;
                o[0] = (_Float16)leaky(acc[bi][bj][i][0] + bias[cc + 0]);
                o[1] = (_Float16)leaky(acc[bi][bj][i][1] + bias[cc + 1]);
                o[2] = (_Float16)leaky(acc[bi][bj][i][2] + bias[cc + 2]);
                o[3] = (_Float16)leaky(acc[bi][bj][i][3] + bias[cc + 3]);
                *reinterpret_cast<h4_t*>(&C[(size_t)rr * 1024 + cc]) = o;
            }
        }
}

// ---------------------------------------------------------------------------
// K3: h2 = leaky(h1 @ W2 + b2) via fp16 MFMA; output PACKED h2t. (unchanged)
// ---------------------------------------------------------------------------
__global__ __launch_bounds__(256) void gemm_mfma_f16(const _Float16* __restrict__ A,
                                                     const _Float16* __restrict__ BT,
                                                     const float* __restrict__ bias,
                                                     _Float16* __restrict__ h2t)
{
    __shared__ alignas(16) _Float16 As[128 * 32];
    __shared__ alignas(16) _Float16 Bs[128 * 32];
    const int tid = threadIdx.x;
    const int l   = tid & 63;
    const int w   = tid >> 6;
    const int wm  = w >> 1;
    const int wn  = w & 1;
    const int bm0 = blockIdx.y * 128;
    const int bn0 = blockIdx.x * 128;
    const int fr  = l & 15;
    const int fg  = l >> 4;
    const int srow  = l >> 2;
    const int sslot = l & 3;

    f32x4 acc[4][4] = {};

    for (int k0 = 0; k0 < 1024; k0 += 32) {
#pragma unroll
        for (int i = 0; i < 2; ++i) {
            const int r0   = (w * 2 + i) * 16;
            const int rowA = r0 + srow;
            const int slot = sslot ^ (rowA & 3);
            __builtin_amdgcn_global_load_lds(
                (const __attribute__((address_space(1))) void*)&A[(size_t)(bm0 + rowA) * 1024 + k0 + slot * 8],
                (__attribute__((address_space(3))) void*)&As[r0 * 32], 16, 0, 0);
            __builtin_amdgcn_global_load_lds(
                (const __attribute__((address_space(1))) void*)&BT[(size_t)(bn0 + rowA) * 1024 + k0 + slot * 8],
                (__attribute__((address_space(3))) void*)&Bs[r0 * 32], 16, 0, 0);
        }
        __syncthreads();

        h8_t af[4], bf[4];
#pragma unroll
        for (int mt = 0; mt < 4; ++mt) {
            int row = wm * 64 + mt * 16 + fr;
            af[mt] = *reinterpret_cast<const h8_t*>(&As[row * 32 + ((fg ^ (row & 3)) << 3)]);
        }
#pragma unroll
        for (int nt = 0; nt < 4; ++nt) {
            int row = wn * 64 + nt * 16 + fr;
            bf[nt] = *reinterpret_cast<const h8_t*>(&Bs[row * 32 + ((fg ^ (row & 3)) << 3)]);
        }
#pragma unroll
        for (int mt = 0; mt < 4; ++mt)
#pragma unroll
            for (int nt = 0; nt < 4; ++nt)
                acc[mt][nt] = __builtin_amdgcn_mfma_f32_16x16x32_f16(af[mt], bf[nt],
                                                                     acc[mt][nt], 0, 0, 0);
        __syncthreads();
    }

    const int rblk0 = (bm0 >> 4) + wm * 4;
    const int cblk0 = (bn0 >> 4) + wn * 4;
#pragma unroll
    for (int nt = 0; nt < 4; ++nt) {
        const int col = bn0 + wn * 64 + nt * 16 + fr;
        const float bv = bias[col];
#pragma unroll
        for (int mt = 0; mt < 4; ++mt) {
            h4_t pk;
#pragma unroll
            for (int r = 0; r < 4; ++r) {
                float v = acc[mt][nt][r] + bv;
                pk[r] = (_Float16)fmaxf(v, NEG_SLOPE * v);
            }
            *reinterpret_cast<h4_t*>(
                &h2t[(((size_t)(cblk0 + nt) * 256 + rblk0 + mt) * 16 + fr) * 16 + fg * 4]) = pk;
        }
    }
}

// ---------------------------------------------------------------------------
// K4: fused additive chain v4 (round-8 version kept; main loop unrolled so
// bias arrays stay in registers — rule #20).
// ---------------------------------------------------------------------------
#define RCH 4

__global__ __launch_bounds__(256) void fused_tail4(const _Float16* __restrict__ h2t,
                                                   const _Float16* __restrict__ wpack,
                                                   const float* __restrict__ a1b,
                                                   const float* __restrict__ a1bias,
                                                   const float* __restrict__ a2b,
                                                   const float* __restrict__ a2bias,
                                                   float* __restrict__ partials)
{
    __shared__ alignas(16) _Float16 stage[2][10240];  // 2 x 20KB
    __shared__ alignas(16) _Float16 act[4][1024];     // per-wave, a then a2 (8KB)

    const int tid = threadIdx.x;
    const int l = tid & 63, w = tid >> 6;
    const int c = l & 15, q = l >> 4;
    const int row0  = blockIdx.x * 64;
    const int rbase = blockIdx.y * RCH;
    const float b1s = a1bias[0], b2s = a2bias[0];

    const unsigned trl   = l * 8;
    const unsigned abase = lds_off(&act[w][0]);

    float b1v[RCH][4], b2v[RCH][4];
#pragma unroll
    for (int rl = 0; rl < RCH; ++rl)
#pragma unroll
        for (int nt = 0; nt < 4; ++nt) {
            b1v[rl][nt] = a1b[(rbase + rl) * 64 + nt * 16 + c] + b1s;
            b2v[rl][nt] = a2b[(rbase + rl) * 64 + nt * 16 + c] + b2s;
        }

    auto STAGE = [&](int rl, int b) {
        const int r = rbase + rl;
        const _Float16* hsrc = h2t + ((size_t)r * 256 + blockIdx.x * 4) * 256;
        const _Float16* wsrc = wpack + (size_t)r * 9216;
#pragma unroll
        for (int i = 0; i < 5; ++i) {
            const int ch = w * 5 + i;
            const _Float16* src = (ch < 2) ? (hsrc + ch * 512) : (wsrc + (ch - 2) * 512);
            __builtin_amdgcn_global_load_lds(
                (const __attribute__((address_space(1))) void*)(src + l * 8),
                (__attribute__((address_space(3))) void*)&stage[b][ch * 512], 16, 0, 0);
        }
    };

    STAGE(0, 0);
    __syncthreads();

    f32x4 accT[4] = {};
    int cur = 0;

#pragma unroll
    for (int rl = 0; rl < RCH; ++rl) {
        if (rl + 1 < RCH) STAGE(rl + 1, cur ^ 1);

        const _Float16* sp = &stage[cur][0];
        const unsigned sbytes = lds_off(sp);

        // ---- phase A: a = leaky(h_slice @ W1r + bias)
        h4_t ha = tr16(sbytes + w * 512 + trl);
        lgkm0();
        f32x4 pa[4];
#pragma unroll
        for (int nt = 0; nt < 4; ++nt) {
            h4_t bf = *reinterpret_cast<const h4_t*>(&sp[1024 + nt * 256 + l * 4]);
            pa[nt] = __builtin_amdgcn_mfma_f32_16x16x16f16(ha, bf, (f32x4){0.f,0.f,0.f,0.f}, 0, 0, 0);
        }
#pragma unroll
        for (int nt = 0; nt < 4; ++nt) {
            h4_t pk;
#pragma unroll
            for (int rg = 0; rg < 4; ++rg) {
                float v = pa[nt][rg] + b1v[rl][nt];
                pk[rg] = (_Float16)fmaxf(v, NEG_SLOPE * v);
            }
            const int kk = nt * 16 + c;
            const int hh = (kk >> 2) & 1;
            const int kp = (kk & 3) | ((kk >> 3) << 2);
            *reinterpret_cast<h4_t*>(&act[w][hh * 512 + kp * 16 + q * 4]) = pk;
        }
        lgkm0();

        // ---- phase B: a2 = leaky(a @ W2r + bias)
        h8_t afB[2];
#pragma unroll
        for (int kt = 0; kt < 2; ++kt) {
            h4_t lo = tr16(abase + kt * 512 + trl);
            h4_t hi = tr16(abase + 1024 + kt * 512 + trl);
            afB[kt] = __builtin_shufflevector(lo, hi, 0, 1, 2, 3, 4, 5, 6, 7);
        }
        lgkm0();
        f32x4 pb[4] = {};
#pragma unroll
        for (int kt = 0; kt < 2; ++kt)
#pragma unroll
            for (int nt = 0; nt < 4; ++nt) {
                h8_t bf = *reinterpret_cast<const h8_t*>(&sp[2048 + kt * 2048 + nt * 512 + l * 8]);
                pb[nt] = __builtin_amdgcn_mfma_f32_16x16x32_f16(afB[kt], bf, pb[nt], 0, 0, 0);
            }
#pragma unroll
        for (int nt = 0; nt < 4; ++nt) {
            h4_t pk;
#pragma unroll
            for (int rg = 0; rg < 4; ++rg) {
                float v = pb[nt][rg] + b2v[rl][nt];
                pk[rg] = (_Float16)fmaxf(v, NEG_SLOPE * v);
            }
            const int kk = nt * 16 + c;
            const int hh = (kk >> 2) & 1;
            const int kp = (kk & 3) | ((kk >> 3) << 2);
            *reinterpret_cast<h4_t*>(&act[w][hh * 512 + kp * 16 + q * 4]) = pk;
        }
        lgkm0();

        // ---- phase C: t2 += a2 @ WpR
        h8_t afC[2];
#pragma unroll
        for (int kt = 0; kt < 2; ++kt) {
            h4_t lo = tr16(abase + kt * 512 + trl);
            h4_t hi = tr16(abase + 1024 + kt * 512 + trl);
            afC[kt] = __builtin_shufflevector(lo, hi, 0, 1, 2, 3, 4, 5, 6, 7);
        }
        lgkm0();
#pragma unroll
        for (int kt = 0; kt < 2; ++kt)
#pragma unroll
            for (int nt = 0; nt < 4; ++nt) {
                h8_t bf = *reinterpret_cast<const h8_t*>(&sp[6144 + kt * 2048 + nt * 512 + l * 8]);
                accT[nt] = __builtin_amdgcn_mfma_f32_16x16x32_f16(afC[kt], bf, accT[nt], 0, 0, 0);
            }

        __syncthreads();
        cur ^= 1;
    }

#pragma unroll
    for (int nt = 0; nt < 4; ++nt)
#pragma unroll
        for (int rg = 0; rg < 4; ++rg)
            partials[((size_t)blockIdx.y * 4096 + row0 + w * 16 + q * 4 + rg) * 64 + nt * 16 + c] =
                accT[nt][rg];
}

// ---------------------------------------------------------------------------
// K5: reduce 16 partials + bp2, dot with Wl, add bl -> out[4096]
// ---------------------------------------------------------------------------
__global__ __launch_bounds__(256) void reduce_out(const float* __restrict__ partials,
                                                  const float* __restrict__ bp2,
                                                  const float* __restrict__ Wl,
                                                  const float* __restrict__ bl,
                                                  float* __restrict__ out)
{
    const int tid = threadIdx.x;
    const int row = blockIdx.x * 4 + (tid >> 6);
    const int col = tid & 63;
    float s = bp2[col];
#pragma unroll
    for (int c = 0; c < 16; ++c)
        s += partials[(size_t)c * 262144 + (size_t)row * 64 + col];
    s *= Wl[col];
    s += __shfl_xor(s, 1);
    s += __shfl_xor(s, 2);
    s += __shfl_xor(s, 4);
    s += __shfl_xor(s, 8);
    s += __shfl_xor(s, 16);
    s += __shfl_xor(s, 32);
    if (col == 0) out[row] = s + bl[0];
}

// ---------------------------------------------------------------------------
extern "C" void kernel_launch(void* const* d_in, const int* in_sizes, int n_in,
                              void* d_out, int out_size, void* d_ws, size_t ws_size,
                              hipStream_t stream)
{
    const float* x      = (const float*)d_in[0];
    const float* Wpca   = (const float*)d_in[1];
    const float* bpca   = (const float*)d_in[2];
    const float* W1     = (const float*)d_in[3];
    const float* b1     = (const float*)d_in[4];
    const float* W2     = (const float*)d_in[5];
    const float* b2     = (const float*)d_in[6];
    const float* a1W    = (const float*)d_in[7];
    const float* a1b    = (const float*)d_in[8];
    const float* a1bias = (const float*)d_in[9];
    const float* a2W    = (const float*)d_in[10];
    const float* a2b    = (const float*)d_in[11];
    const float* a2bias = (const float*)d_in[12];
    const float* Wp2    = (const float*)d_in[13];
    const float* bp2    = (const float*)d_in[14];
    const float* Wl     = (const float*)d_in[15];
    const float* bl     = (const float*)d_in[16];
    float* out = (float*)d_out;

    // workspace layout (bytes)
    char* wsb = (char*)d_ws;
    float*    t        = (float*)   (wsb);                         // 1 MB
    _Float16* h1h      = (_Float16*)(wsb + (1ull  << 20));         // 8 MB
    _Float16* h2t      = (_Float16*)(wsb + (9ull  << 20));         // 8 MB
    _Float16* W2T      = (_Float16*)(wsb + (17ull << 20));         // 2 MB
    _Float16* wpack    = (_Float16*)(wsb + (19ull << 20));         // 1.2 MB
    float*    partials = (float*)   (wsb + (21ull << 20));         // 16.8 MB
    float*    tpart    = (float*)   (wsb + (9ull  << 20));         // aliases h2t (dead then)

    // prep: W2T + wpack in one launch
    prep_weights<<<dim3(3328), 256, 0, stream>>>(W2, a1W, a2W, Wp2, W2T, wpack);
    // t = x @ W_pca + b_pca  (split-K fp32 + combine)
    gemm_n64_splitk<<<dim3(128, 8), 256, 0, stream>>>(x, Wpca, tpart);
    combine_t<<<dim3(1024), 256, 0, stream>>>(tpart, bpca, t);
    // h1 = leaky(t @ W1 + b1) -> fp16   (proven fp32 VALU kernel, K=64)
    gemm_n1024_f16out<<<dim3(8, 32), 256, 0, stream>>>(t, W1, b1, h1h, 64);
    // h2 (packed) = leaky(h1 @ W2 + b2) via MFMA
    gemm_mfma_f16<<<dim3(8, 32), 256, 0, stream>>>(h1h, W2T, b2, h2t);
    // fused additive chain (MFMA) -> partial t2 per r-chunk
    fused_tail4<<<dim3(64, 16), 256, 0, stream>>>(h2t, wpack, a1b, a1bias,
                                                  a2b, a2bias, partials);
    // reduce partials + PCA2 bias + last layer
    reduce_out<<<dim3(1024), 256, 0, stream>>>(partials, bp2, Wl, bl, out);
}

// Round 10
// 73.584 us; speedup vs baseline: 6.4963x; 1.1215x over previous
//
#include <hip/hip_runtime.h>

#define NEG_SLOPE 0.1f

__device__ __forceinline__ float leaky(float v) { return v > 0.0f ? v : NEG_SLOPE * v; }

typedef _Float16 h4_t __attribute__((ext_vector_type(4)));
typedef _Float16 h8_t __attribute__((ext_vector_type(8)));
typedef float f32x4 __attribute__((ext_vector_type(4)));

__device__ __forceinline__ unsigned lds_off(const void* p) {
    return (unsigned)(unsigned long long)p;
}

__device__ __forceinline__ void lgkm0() {
    asm volatile("s_waitcnt lgkmcnt(0)" ::: "memory");
    __builtin_amdgcn_sched_barrier(0);        // rule #18
}

__device__ __forceinline__ h4_t tr16(unsigned addr) {
    h4_t d;
    asm volatile("ds_read_b64_tr_b16 %0, %1" : "=v"(d) : "v"(addr) : "memory");
    return d;
}

// ---------------------------------------------------------------------------
// PREP: W2T (fp16) + W1T (fp16) + tail-weight packing in one launch.
// blocks [0,1024): W2T; [1024,1088): W1T; [1088,3392): pack.
// ---------------------------------------------------------------------------
__global__ __launch_bounds__(256) void prep_weights(const float* __restrict__ W2,
                                                    const float* __restrict__ W1,
                                                    const float* __restrict__ a1W,
                                                    const float* __restrict__ a2W,
                                                    const float* __restrict__ Wp2,
                                                    _Float16* __restrict__ W2T,
                                                    _Float16* __restrict__ W1T,
                                                    _Float16* __restrict__ wpack)
{
    __shared__ float tile[32][33];
    const int b   = blockIdx.x;
    const int tid = threadIdx.x;

    if (b < 1024) {                         // W2T[n][k] = fp16 W2[k][n]
        const int n0 = (b & 31) * 32, k0 = (b >> 5) * 32;
        const int r = tid >> 3, c4 = (tid & 7) * 4;
        float4 v = *reinterpret_cast<const float4*>(&W2[(size_t)(k0 + r) * 1024 + n0 + c4]);
        tile[r][c4 + 0] = v.x; tile[r][c4 + 1] = v.y;
        tile[r][c4 + 2] = v.z; tile[r][c4 + 3] = v.w;
        __syncthreads();
        h4_t o;
        o[0] = (_Float16)tile[c4 + 0][r]; o[1] = (_Float16)tile[c4 + 1][r];
        o[2] = (_Float16)tile[c4 + 2][r]; o[3] = (_Float16)tile[c4 + 3][r];
        *reinterpret_cast<h4_t*>(&W2T[(size_t)(n0 + r) * 1024 + k0 + c4]) = o;
    } else if (b < 1088) {                  // W1T[n][k] = fp16 W1[k][n]  (k<64)
        const int b2 = b - 1024;
        const int n0 = (b2 & 31) * 32, k0 = (b2 >> 5) * 32;
        const int r = tid >> 3, c4 = (tid & 7) * 4;
        float4 v = *reinterpret_cast<const float4*>(&W1[(size_t)(k0 + r) * 1024 + n0 + c4]);
        tile[r][c4 + 0] = v.x; tile[r][c4 + 1] = v.y;
        tile[r][c4 + 2] = v.z; tile[r][c4 + 3] = v.w;
        __syncthreads();
        h4_t o;
        o[0] = (_Float16)tile[c4 + 0][r]; o[1] = (_Float16)tile[c4 + 1][r];
        o[2] = (_Float16)tile[c4 + 2][r]; o[3] = (_Float16)tile[c4 + 3][r];
        *reinterpret_cast<h4_t*>(&W1T[(size_t)(n0 + r) * 64 + k0 + c4]) = o;
    } else {                                // pack tail weights (MFMA B-frag order)
        const int idx = (b - 1088) * 256 + tid;   // < 589824
        if (idx < 589824) {
            const int r = idx / 9216, qq = idx % 9216;
            float v;
            if (qq < 1024) {
                int nt = qq >> 8, rem = qq & 255, l = rem >> 2, j = rem & 3;
                int n = nt * 16 + (l & 15), k = (l >> 4) * 4 + j;
                v = a1W[(size_t)r * 1024 + k * 64 + n];
            } else if (qq < 5120) {
                int p = qq - 1024, kt = p >> 11, u = p & 2047, nt = u >> 9, s = u & 511,
                    l = s >> 3, j = s & 7;
                int n = nt * 16 + (l & 15), k = kt * 32 + (l >> 4) * 8 + j;
                v = a2W[(size_t)r * 4096 + k * 64 + n];
            } else {
                int p = qq - 5120, kt = p >> 11, u = p & 2047, nt = u >> 9, s = u & 511,
                    l = s >> 3, j = s & 7;
                int n = nt * 16 + (l & 15), k = kt * 32 + (l >> 4) * 8 + j;
                v = Wp2[((size_t)r * 64 + k) * 64 + n];
            }
            wpack[idx] = (_Float16)v;
        }
    }
}

// ---------------------------------------------------------------------------
// K1: split-K fp32 GEMM for t = x @ W_pca. Partials [8][4096][64].
// ---------------------------------------------------------------------------
__global__ __launch_bounds__(256) void gemm_n64_splitk(const float* __restrict__ A,
                                                       const float* __restrict__ B,
                                                       float* __restrict__ P)
{
    __shared__ alignas(16) float As[32][33];
    __shared__ alignas(16) float Bs[32][64];
    const int tid   = threadIdx.x;
    const int row0  = blockIdx.x * 32;
    const int kbase = blockIdx.y * 128;
    const int r0    = (tid >> 4) * 2;
    const int c0    = (tid & 15) * 4;
    const int am    = tid >> 3;
    const int ak    = (tid & 7) * 4;
    float acc[2][4] = {};

#pragma unroll
    for (int kc = 0; kc < 128; kc += 32) {
        const int k0 = kbase + kc;
        float4 va = *reinterpret_cast<const float4*>(&A[(size_t)(row0 + am) * 1024 + k0 + ak]);
        As[ak + 0][am] = va.x; As[ak + 1][am] = va.y;
        As[ak + 2][am] = va.z; As[ak + 3][am] = va.w;
#pragma unroll
        for (int p = 0; p < 2; ++p) {
            int idx = tid + p * 256;
            int kk  = idx >> 4;
            int nq  = (idx & 15) * 4;
            *reinterpret_cast<float4*>(&Bs[kk][nq]) =
                *reinterpret_cast<const float4*>(&B[(size_t)(k0 + kk) * 64 + nq]);
        }
        __syncthreads();
#pragma unroll
        for (int k = 0; k < 32; ++k) {
            float a0 = As[k][r0], a1 = As[k][r0 + 1];
            float4 bv = *reinterpret_cast<const float4*>(&Bs[k][c0]);
            acc[0][0] = fmaf(a0, bv.x, acc[0][0]); acc[0][1] = fmaf(a0, bv.y, acc[0][1]);
            acc[0][2] = fmaf(a0, bv.z, acc[0][2]); acc[0][3] = fmaf(a0, bv.w, acc[0][3]);
            acc[1][0] = fmaf(a1, bv.x, acc[1][0]); acc[1][1] = fmaf(a1, bv.y, acc[1][1]);
            acc[1][2] = fmaf(a1, bv.z, acc[1][2]); acc[1][3] = fmaf(a1, bv.w, acc[1][3]);
        }
        __syncthreads();
    }
#pragma unroll
    for (int i = 0; i < 2; ++i) {
        float4 o; o.x = acc[i][0]; o.y = acc[i][1]; o.z = acc[i][2]; o.w = acc[i][3];
        *reinterpret_cast<float4*>(
            &P[((size_t)blockIdx.y * 4096 + row0 + r0 + i) * 64 + c0]) = o;
    }
}

// K1b: t16 = fp16(sum_c P[c] + bias)
__global__ __launch_bounds__(256) void combine_t16(const float* __restrict__ P,
                                                   const float* __restrict__ bias,
                                                   _Float16* __restrict__ t16)
{
    const int idx = blockIdx.x * 256 + threadIdx.x;
    float s = bias[idx & 63];
#pragma unroll
    for (int c = 0; c < 8; ++c)
        s += P[(size_t)c * 262144 + idx];
    t16[idx] = (_Float16)s;
}

// ---------------------------------------------------------------------------
// K2: h1[4096][1024] = leaky(t16 @ W1 + b1) via fp16 MFMA (K=64).
// A = t16 [4096][64]; BT = W1T [1024][64]. Whole-K staged tiles; 8-slot XOR
// involution (LDS[row][s] = global[row][s^(row&7)], read slot sg^(row&7)).
// ---------------------------------------------------------------------------
__global__ __launch_bounds__(256) void gemm_k64_mfma(const _Float16* __restrict__ A,
                                                     const _Float16* __restrict__ BT,
                                                     const float* __restrict__ bias,
                                                     _Float16* __restrict__ C)
{
    __shared__ alignas(16) _Float16 As[128 * 64];
    __shared__ alignas(16) _Float16 Bs[128 * 64];
    const int tid = threadIdx.x;
    const int l   = tid & 63;
    const int w   = tid >> 6;
    const int wm  = w >> 1;
    const int wn  = w & 1;
    const int bm0 = blockIdx.y * 128;
    const int bn0 = blockIdx.x * 128;
    const int fr  = l & 15;
    const int fg  = l >> 4;
    const int srow  = l >> 3;            // 8 rows / issue
    const int sslot = l & 7;             // 8 x 16B slots / 128B row

#pragma unroll
    for (int i = 0; i < 4; ++i) {
        const int r0   = w * 32 + i * 8;
        const int rowA = r0 + srow;
        const int slot = sslot ^ (rowA & 7);
        __builtin_amdgcn_global_load_lds(
            (const __attribute__((address_space(1))) void*)&A[(size_t)(bm0 + rowA) * 64 + slot * 8],
            (__attribute__((address_space(3))) void*)&As[r0 * 64], 16, 0, 0);
        __builtin_amdgcn_global_load_lds(
            (const __attribute__((address_space(1))) void*)&BT[(size_t)(bn0 + rowA) * 64 + slot * 8],
            (__attribute__((address_space(3))) void*)&Bs[r0 * 64], 16, 0, 0);
    }
    __syncthreads();

    f32x4 acc[4][4] = {};
#pragma unroll
    for (int ks = 0; ks < 2; ++ks) {
        h8_t af[4], bf[4];
#pragma unroll
        for (int mt = 0; mt < 4; ++mt) {
            int row = wm * 64 + mt * 16 + fr;
            int sg  = ks * 4 + fg;
            af[mt] = *reinterpret_cast<const h8_t*>(&As[row * 64 + ((sg ^ (row & 7)) << 3)]);
        }
#pragma unroll
        for (int nt = 0; nt < 4; ++nt) {
            int row = wn * 64 + nt * 16 + fr;
            int sg  = ks * 4 + fg;
            bf[nt] = *reinterpret_cast<const h8_t*>(&Bs[row * 64 + ((sg ^ (row & 7)) << 3)]);
        }
#pragma unroll
        for (int mt = 0; mt < 4; ++mt)
#pragma unroll
            for (int nt = 0; nt < 4; ++nt)
                acc[mt][nt] = __builtin_amdgcn_mfma_f32_16x16x32_f16(af[mt], bf[nt],
                                                                     acc[mt][nt], 0, 0, 0);
    }

#pragma unroll
    for (int nt = 0; nt < 4; ++nt) {
        const int col = bn0 + wn * 64 + nt * 16 + fr;
        const float bv = bias[col];
#pragma unroll
        for (int mt = 0; mt < 4; ++mt)
#pragma unroll
            for (int rg = 0; rg < 4; ++rg) {
                const int row = bm0 + wm * 64 + mt * 16 + fg * 4 + rg;
                float v = acc[mt][nt][rg] + bv;
                C[(size_t)row * 1024 + col] = (_Float16)fmaxf(v, NEG_SLOPE * v);
            }
    }
}

// ---------------------------------------------------------------------------
// K3: h2 = leaky(h1 @ W2 + b2) via fp16 MFMA; output PACKED h2t. (unchanged)
// ---------------------------------------------------------------------------
__global__ __launch_bounds__(256) void gemm_mfma_f16(const _Float16* __restrict__ A,
                                                     const _Float16* __restrict__ BT,
                                                     const float* __restrict__ bias,
                                                     _Float16* __restrict__ h2t)
{
    __shared__ alignas(16) _Float16 As[128 * 32];
    __shared__ alignas(16) _Float16 Bs[128 * 32];
    const int tid = threadIdx.x;
    const int l   = tid & 63;
    const int w   = tid >> 6;
    const int wm  = w >> 1;
    const int wn  = w & 1;
    const int bm0 = blockIdx.y * 128;
    const int bn0 = blockIdx.x * 128;
    const int fr  = l & 15;
    const int fg  = l >> 4;
    const int srow  = l >> 2;
    const int sslot = l & 3;

    f32x4 acc[4][4] = {};

    for (int k0 = 0; k0 < 1024; k0 += 32) {
#pragma unroll
        for (int i = 0; i < 2; ++i) {
            const int r0   = (w * 2 + i) * 16;
            const int rowA = r0 + srow;
            const int slot = sslot ^ (rowA & 3);
            __builtin_amdgcn_global_load_lds(
                (const __attribute__((address_space(1))) void*)&A[(size_t)(bm0 + rowA) * 1024 + k0 + slot * 8],
                (__attribute__((address_space(3))) void*)&As[r0 * 32], 16, 0, 0);
            __builtin_amdgcn_global_load_lds(
                (const __attribute__((address_space(1))) void*)&BT[(size_t)(bn0 + rowA) * 1024 + k0 + slot * 8],
                (__attribute__((address_space(3))) void*)&Bs[r0 * 32], 16, 0, 0);
        }
        __syncthreads();

        h8_t af[4], bf[4];
#pragma unroll
        for (int mt = 0; mt < 4; ++mt) {
            int row = wm * 64 + mt * 16 + fr;
            af[mt] = *reinterpret_cast<const h8_t*>(&As[row * 32 + ((fg ^ (row & 3)) << 3)]);
        }
#pragma unroll
        for (int nt = 0; nt < 4; ++nt) {
            int row = wn * 64 + nt * 16 + fr;
            bf[nt] = *reinterpret_cast<const h8_t*>(&Bs[row * 32 + ((fg ^ (row & 3)) << 3)]);
        }
#pragma unroll
        for (int mt = 0; mt < 4; ++mt)
#pragma unroll
            for (int nt = 0; nt < 4; ++nt)
                acc[mt][nt] = __builtin_amdgcn_mfma_f32_16x16x32_f16(af[mt], bf[nt],
                                                                     acc[mt][nt], 0, 0, 0);
        __syncthreads();
    }

    const int rblk0 = (bm0 >> 4) + wm * 4;
    const int cblk0 = (bn0 >> 4) + wn * 4;
#pragma unroll
    for (int nt = 0; nt < 4; ++nt) {
        const int col = bn0 + wn * 64 + nt * 16 + fr;
        const float bv = bias[col];
#pragma unroll
        for (int mt = 0; mt < 4; ++mt) {
            h4_t pk;
#pragma unroll
            for (int r = 0; r < 4; ++r) {
                float v = acc[mt][nt][r] + bv;
                pk[r] = (_Float16)fmaxf(v, NEG_SLOPE * v);
            }
            *reinterpret_cast<h4_t*>(
                &h2t[(((size_t)(cblk0 + nt) * 256 + rblk0 + mt) * 16 + fr) * 16 + fg * 4]) = pk;
        }
    }
}

// ---------------------------------------------------------------------------
// K4: fused additive chain v4 (unchanged from passing round 9)
// ---------------------------------------------------------------------------
#define RCH 4

__global__ __launch_bounds__(256) void fused_tail4(const _Float16* __restrict__ h2t,
                                                   const _Float16* __restrict__ wpack,
                                                   const float* __restrict__ a1b,
                                                   const float* __restrict__ a1bias,
                                                   const float* __restrict__ a2b,
                                                   const float* __restrict__ a2bias,
                                                   float* __restrict__ partials)
{
    __shared__ alignas(16) _Float16 stage[2][10240];  // 2 x 20KB
    __shared__ alignas(16) _Float16 act[4][1024];     // per-wave, a then a2 (8KB)

    const int tid = threadIdx.x;
    const int l = tid & 63, w = tid >> 6;
    const int c = l & 15, q = l >> 4;
    const int row0  = blockIdx.x * 64;
    const int rbase = blockIdx.y * RCH;
    const float b1s = a1bias[0], b2s = a2bias[0];

    const unsigned trl   = l * 8;
    const unsigned abase = lds_off(&act[w][0]);

    float b1v[RCH][4], b2v[RCH][4];
#pragma unroll
    for (int rl = 0; rl < RCH; ++rl)
#pragma unroll
        for (int nt = 0; nt < 4; ++nt) {
            b1v[rl][nt] = a1b[(rbase + rl) * 64 + nt * 16 + c] + b1s;
            b2v[rl][nt] = a2b[(rbase + rl) * 64 + nt * 16 + c] + b2s;
        }

    auto STAGE = [&](int rl, int b) {
        const int r = rbase + rl;
        const _Float16* hsrc = h2t + ((size_t)r * 256 + blockIdx.x * 4) * 256;
        const _Float16* wsrc = wpack + (size_t)r * 9216;
#pragma unroll
        for (int i = 0; i < 5; ++i) {
            const int ch = w * 5 + i;
            const _Float16* src = (ch < 2) ? (hsrc + ch * 512) : (wsrc + (ch - 2) * 512);
            __builtin_amdgcn_global_load_lds(
                (const __attribute__((address_space(1))) void*)(src + l * 8),
                (__attribute__((address_space(3))) void*)&stage[b][ch * 512], 16, 0, 0);
        }
    };

    STAGE(0, 0);
    __syncthreads();

    f32x4 accT[4] = {};
    int cur = 0;

#pragma unroll
    for (int rl = 0; rl < RCH; ++rl) {
        if (rl + 1 < RCH) STAGE(rl + 1, cur ^ 1);

        const _Float16* sp = &stage[cur][0];
        const unsigned sbytes = lds_off(sp);

        // ---- phase A: a = leaky(h_slice @ W1r + bias)
        h4_t ha = tr16(sbytes + w * 512 + trl);
        lgkm0();
        f32x4 pa[4];
#pragma unroll
        for (int nt = 0; nt < 4; ++nt) {
            h4_t bf = *reinterpret_cast<const h4_t*>(&sp[1024 + nt * 256 + l * 4]);
            pa[nt] = __builtin_amdgcn_mfma_f32_16x16x16f16(ha, bf, (f32x4){0.f,0.f,0.f,0.f}, 0, 0, 0);
        }
#pragma unroll
        for (int nt = 0; nt < 4; ++nt) {
            h4_t pk;
#pragma unroll
            for (int rg = 0; rg < 4; ++rg) {
                float v = pa[nt][rg] + b1v[rl][nt];
                pk[rg] = (_Float16)fmaxf(v, NEG_SLOPE * v);
            }
            const int kk = nt * 16 + c;
            const int hh = (kk >> 2) & 1;
            const int kp = (kk & 3) | ((kk >> 3) << 2);
            *reinterpret_cast<h4_t*>(&act[w][hh * 512 + kp * 16 + q * 4]) = pk;
        }
        lgkm0();

        // ---- phase B: a2 = leaky(a @ W2r + bias)
        h8_t afB[2];
#pragma unroll
        for (int kt = 0; kt < 2; ++kt) {
            h4_t lo = tr16(abase + kt * 512 + trl);
            h4_t hi = tr16(abase + 1024 + kt * 512 + trl);
            afB[kt] = __builtin_shufflevector(lo, hi, 0, 1, 2, 3, 4, 5, 6, 7);
        }
        lgkm0();
        f32x4 pb[4] = {};
#pragma unroll
        for (int kt = 0; kt < 2; ++kt)
#pragma unroll
            for (int nt = 0; nt < 4; ++nt) {
                h8_t bf = *reinterpret_cast<const h8_t*>(&sp[2048 + kt * 2048 + nt * 512 + l * 8]);
                pb[nt] = __builtin_amdgcn_mfma_f32_16x16x32_f16(afB[kt], bf, pb[nt], 0, 0, 0);
            }
#pragma unroll
        for (int nt = 0; nt < 4; ++nt) {
            h4_t pk;
#pragma unroll
            for (int rg = 0; rg < 4; ++rg) {
                float v = pb[nt][rg] + b2v[rl][nt];
                pk[rg] = (_Float16)fmaxf(v, NEG_SLOPE * v);
            }
            const int kk = nt * 16 + c;
            const int hh = (kk >> 2) & 1;
            const int kp = (kk & 3) | ((kk >> 3) << 2);
            *reinterpret_cast<h4_t*>(&act[w][hh * 512 + kp * 16 + q * 4]) = pk;
        }
        lgkm0();

        // ---- phase C: t2 += a2 @ WpR
        h8_t afC[2];
#pragma unroll
        for (int kt = 0; kt < 2; ++kt) {
            h4_t lo = tr16(abase + kt * 512 + trl);
            h4_t hi = tr16(abase + 1024 + kt * 512 + trl);
            afC[kt] = __builtin_shufflevector(lo, hi, 0, 1, 2, 3, 4, 5, 6, 7);
        }
        lgkm0();
#pragma unroll
        for (int kt = 0; kt < 2; ++kt)
#pragma unroll
            for (int nt = 0; nt < 4; ++nt) {
                h8_t bf = *reinterpret_cast<const h8_t*>(&sp[6144 + kt * 2048 + nt * 512 + l * 8]);
                accT[nt] = __builtin_amdgcn_mfma_f32_16x16x32_f16(afC[kt], bf, accT[nt], 0, 0, 0);
            }

        __syncthreads();
        cur ^= 1;
    }

#pragma unroll
    for (int nt = 0; nt < 4; ++nt)
#pragma unroll
        for (int rg = 0; rg < 4; ++rg)
            partials[((size_t)blockIdx.y * 4096 + row0 + w * 16 + q * 4 + rg) * 64 + nt * 16 + c] =
                accT[nt][rg];
}

// ---------------------------------------------------------------------------
// K5: reduce 16 partials + bp2, dot with Wl, add bl -> out[4096]
// ---------------------------------------------------------------------------
__global__ __launch_bounds__(256) void reduce_out(const float* __restrict__ partials,
                                                  const float* __restrict__ bp2,
                                                  const float* __restrict__ Wl,
                                                  const float* __restrict__ bl,
                                                  float* __restrict__ out)
{
    const int tid = threadIdx.x;
    const int row = blockIdx.x * 4 + (tid >> 6);
    const int col = tid & 63;
    float s = bp2[col];
#pragma unroll
    for (int c = 0; c < 16; ++c)
        s += partials[(size_t)c * 262144 + (size_t)row * 64 + col];
    s *= Wl[col];
    s += __shfl_xor(s, 1);
    s += __shfl_xor(s, 2);
    s += __shfl_xor(s, 4);
    s += __shfl_xor(s, 8);
    s += __shfl_xor(s, 16);
    s += __shfl_xor(s, 32);
    if (col == 0) out[row] = s + bl[0];
}

// ---------------------------------------------------------------------------
extern "C" void kernel_launch(void* const* d_in, const int* in_sizes, int n_in,
                              void* d_out, int out_size, void* d_ws, size_t ws_size,
                              hipStream_t stream)
{
    const float* x      = (const float*)d_in[0];
    const float* Wpca   = (const float*)d_in[1];
    const float* bpca   = (const float*)d_in[2];
    const float* W1     = (const float*)d_in[3];
    const float* b1     = (const float*)d_in[4];
    const float* W2     = (const float*)d_in[5];
    const float* b2     = (const float*)d_in[6];
    const float* a1W    = (const float*)d_in[7];
    const float* a1b    = (const float*)d_in[8];
    const float* a1bias = (const float*)d_in[9];
    const float* a2W    = (const float*)d_in[10];
    const float* a2b    = (const float*)d_in[11];
    const float* a2bias = (const float*)d_in[12];
    const float* Wp2    = (const float*)d_in[13];
    const float* bp2    = (const float*)d_in[14];
    const float* Wl     = (const float*)d_in[15];
    const float* bl     = (const float*)d_in[16];
    float* out = (float*)d_out;

    // workspace layout (bytes) — verified non-overlapping:
    //   t16      [0,          0.5 MB)
    //   h1h      [1 MB,       9 MB)
    //   h2t      [9 MB,      17 MB)   (tpart aliases this, dead before K3)
    //   W2T      [17 MB,     19 MB)
    //   wpack    [19 MB,     20.13 MB)   (589824 fp16 = 1.125 MB)
    //   W1T      [21 MB,     21.125 MB)
    //   partials [22 MB,     38.8 MB)
    char* wsb = (char*)d_ws;
    _Float16* t16      = (_Float16*)(wsb);
    _Float16* h1h      = (_Float16*)(wsb + (1ull  << 20));
    _Float16* h2t      = (_Float16*)(wsb + (9ull  << 20));
    _Float16* W2T      = (_Float16*)(wsb + (17ull << 20));
    _Float16* wpack    = (_Float16*)(wsb + (19ull << 20));
    _Float16* W1T      = (_Float16*)(wsb + (21ull << 20));
    float*    partials = (float*)   (wsb + (22ull << 20));
    float*    tpart    = (float*)   (wsb + (9ull  << 20));

    // prep: W2T + W1T + wpack in one launch
    prep_weights<<<dim3(3392), 256, 0, stream>>>(W2, W1, a1W, a2W, Wp2, W2T, W1T, wpack);
    // t = x @ W_pca + b_pca  (split-K fp32, combine -> fp16)
    gemm_n64_splitk<<<dim3(128, 8), 256, 0, stream>>>(x, Wpca, tpart);
    combine_t16<<<dim3(1024), 256, 0, stream>>>(tpart, bpca, t16);
    // h1 = leaky(t @ W1 + b1) via MFMA (K=64) -> linear fp16
    gemm_k64_mfma<<<dim3(8, 32), 256, 0, stream>>>(t16, W1T, b1, h1h);
    // h2 (packed) = leaky(h1 @ W2 + b2) via MFMA
    gemm_mfma_f16<<<dim3(8, 32), 256, 0, stream>>>(h1h, W2T, b2, h2t);
    // fused additive chain (MFMA) -> partial t2 per r-chunk
    fused_tail4<<<dim3(64, 16), 256, 0, stream>>>(h2t, wpack, a1b, a1bias,
                                                  a2b, a2bias, partials);
    // reduce partials + PCA2 bias + last layer
    reduce_out<<<dim3(1024), 256, 0, stream>>>(partials, bp2, Wl, bl, out);
}

// Round 11
// 65.102 us; speedup vs baseline: 7.3427x; 1.1303x over previous
//
#include <hip/hip_runtime.h>

#define NEG_SLOPE 0.1f

__device__ __forceinline__ float leaky(float v) { return v > 0.0f ? v : NEG_SLOPE * v; }

typedef _Float16 h4_t __attribute__((ext_vector_type(4)));
typedef _Float16 h8_t __attribute__((ext_vector_type(8)));
typedef float f32x4 __attribute__((ext_vector_type(4)));

__device__ __forceinline__ unsigned lds_off(const void* p) {
    return (unsigned)(unsigned long long)p;
}

__device__ __forceinline__ void lgkm0() {
    asm volatile("s_waitcnt lgkmcnt(0)" ::: "memory");
    __builtin_amdgcn_sched_barrier(0);        // rule #18
}

__device__ __forceinline__ h4_t tr16(unsigned addr) {
    h4_t d;
    asm volatile("ds_read_b64_tr_b16 %0, %1" : "=v"(d) : "v"(addr) : "memory");
    return d;
}

// ---------------------------------------------------------------------------
// PREP: W2T (fp16) + W1T (fp16) + tail-weight packing in one launch.
// ---------------------------------------------------------------------------
__global__ __launch_bounds__(256) void prep_weights(const float* __restrict__ W2,
                                                    const float* __restrict__ W1,
                                                    const float* __restrict__ a1W,
                                                    const float* __restrict__ a2W,
                                                    const float* __restrict__ Wp2,
                                                    _Float16* __restrict__ W2T,
                                                    _Float16* __restrict__ W1T,
                                                    _Float16* __restrict__ wpack)
{
    __shared__ float tile[32][33];
    const int b   = blockIdx.x;
    const int tid = threadIdx.x;

    if (b < 1024) {                         // W2T[n][k] = fp16 W2[k][n]
        const int n0 = (b & 31) * 32, k0 = (b >> 5) * 32;
        const int r = tid >> 3, c4 = (tid & 7) * 4;
        float4 v = *reinterpret_cast<const float4*>(&W2[(size_t)(k0 + r) * 1024 + n0 + c4]);
        tile[r][c4 + 0] = v.x; tile[r][c4 + 1] = v.y;
        tile[r][c4 + 2] = v.z; tile[r][c4 + 3] = v.w;
        __syncthreads();
        h4_t o;
        o[0] = (_Float16)tile[c4 + 0][r]; o[1] = (_Float16)tile[c4 + 1][r];
        o[2] = (_Float16)tile[c4 + 2][r]; o[3] = (_Float16)tile[c4 + 3][r];
        *reinterpret_cast<h4_t*>(&W2T[(size_t)(n0 + r) * 1024 + k0 + c4]) = o;
    } else if (b < 1088) {                  // W1T[n][k] = fp16 W1[k][n]  (k<64)
        const int b2 = b - 1024;
        const int n0 = (b2 & 31) * 32, k0 = (b2 >> 5) * 32;
        const int r = tid >> 3, c4 = (tid & 7) * 4;
        float4 v = *reinterpret_cast<const float4*>(&W1[(size_t)(k0 + r) * 1024 + n0 + c4]);
        tile[r][c4 + 0] = v.x; tile[r][c4 + 1] = v.y;
        tile[r][c4 + 2] = v.z; tile[r][c4 + 3] = v.w;
        __syncthreads();
        h4_t o;
        o[0] = (_Float16)tile[c4 + 0][r]; o[1] = (_Float16)tile[c4 + 1][r];
        o[2] = (_Float16)tile[c4 + 2][r]; o[3] = (_Float16)tile[c4 + 3][r];
        *reinterpret_cast<h4_t*>(&W1T[(size_t)(n0 + r) * 64 + k0 + c4]) = o;
    } else {                                // pack tail weights (MFMA B-frag order)
        const int idx = (b - 1088) * 256 + tid;   // < 589824
        if (idx < 589824) {
            const int r = idx / 9216, qq = idx % 9216;
            float v;
            if (qq < 1024) {
                int nt = qq >> 8, rem = qq & 255, l = rem >> 2, j = rem & 3;
                int n = nt * 16 + (l & 15), k = (l >> 4) * 4 + j;
                v = a1W[(size_t)r * 1024 + k * 64 + n];
            } else if (qq < 5120) {
                int p = qq - 1024, kt = p >> 11, u = p & 2047, nt = u >> 9, s = u & 511,
                    l = s >> 3, j = s & 7;
                int n = nt * 16 + (l & 15), k = kt * 32 + (l >> 4) * 8 + j;
                v = a2W[(size_t)r * 4096 + k * 64 + n];
            } else {
                int p = qq - 5120, kt = p >> 11, u = p & 2047, nt = u >> 9, s = u & 511,
                    l = s >> 3, j = s & 7;
                int n = nt * 16 + (l & 15), k = kt * 32 + (l >> 4) * 8 + j;
                v = Wp2[((size_t)r * 64 + k) * 64 + n];
            }
            wpack[idx] = (_Float16)v;
        }
    }
}

// ---------------------------------------------------------------------------
// K1: split-K fp32 GEMM for t = x @ W_pca. Partials [8][4096][64].
// ---------------------------------------------------------------------------
__global__ __launch_bounds__(256) void gemm_n64_splitk(const float* __restrict__ A,
                                                       const float* __restrict__ B,
                                                       float* __restrict__ P)
{
    __shared__ alignas(16) float As[32][33];
    __shared__ alignas(16) float Bs[32][64];
    const int tid   = threadIdx.x;
    const int row0  = blockIdx.x * 32;
    const int kbase = blockIdx.y * 128;
    const int r0    = (tid >> 4) * 2;
    const int c0    = (tid & 15) * 4;
    const int am    = tid >> 3;
    const int ak    = (tid & 7) * 4;
    float acc[2][4] = {};

#pragma unroll
    for (int kc = 0; kc < 128; kc += 32) {
        const int k0 = kbase + kc;
        float4 va = *reinterpret_cast<const float4*>(&A[(size_t)(row0 + am) * 1024 + k0 + ak]);
        As[ak + 0][am] = va.x; As[ak + 1][am] = va.y;
        As[ak + 2][am] = va.z; As[ak + 3][am] = va.w;
#pragma unroll
        for (int p = 0; p < 2; ++p) {
            int idx = tid + p * 256;
            int kk  = idx >> 4;
            int nq  = (idx & 15) * 4;
            *reinterpret_cast<float4*>(&Bs[kk][nq]) =
                *reinterpret_cast<const float4*>(&B[(size_t)(k0 + kk) * 64 + nq]);
        }
        __syncthreads();
#pragma unroll
        for (int k = 0; k < 32; ++k) {
            float a0 = As[k][r0], a1 = As[k][r0 + 1];
            float4 bv = *reinterpret_cast<const float4*>(&Bs[k][c0]);
            acc[0][0] = fmaf(a0, bv.x, acc[0][0]); acc[0][1] = fmaf(a0, bv.y, acc[0][1]);
            acc[0][2] = fmaf(a0, bv.z, acc[0][2]); acc[0][3] = fmaf(a0, bv.w, acc[0][3]);
            acc[1][0] = fmaf(a1, bv.x, acc[1][0]); acc[1][1] = fmaf(a1, bv.y, acc[1][1]);
            acc[1][2] = fmaf(a1, bv.z, acc[1][2]); acc[1][3] = fmaf(a1, bv.w, acc[1][3]);
        }
        __syncthreads();
    }
#pragma unroll
    for (int i = 0; i < 2; ++i) {
        float4 o; o.x = acc[i][0]; o.y = acc[i][1]; o.z = acc[i][2]; o.w = acc[i][3];
        *reinterpret_cast<float4*>(
            &P[((size_t)blockIdx.y * 4096 + row0 + r0 + i) * 64 + c0]) = o;
    }
}

// K1b: t16 = fp16(sum_c P[c] + bias)
__global__ __launch_bounds__(256) void combine_t16(const float* __restrict__ P,
                                                   const float* __restrict__ bias,
                                                   _Float16* __restrict__ t16)
{
    const int idx = blockIdx.x * 256 + threadIdx.x;
    float s = bias[idx & 63];
#pragma unroll
    for (int c = 0; c < 8; ++c)
        s += P[(size_t)c * 262144 + idx];
    t16[idx] = (_Float16)s;
}

// ---------------------------------------------------------------------------
// K2: h1[4096][1024] = leaky(t16 @ W1 + b1) via fp16 MFMA (K=64). (unchanged)
// ---------------------------------------------------------------------------
__global__ __launch_bounds__(256) void gemm_k64_mfma(const _Float16* __restrict__ A,
                                                     const _Float16* __restrict__ BT,
                                                     const float* __restrict__ bias,
                                                     _Float16* __restrict__ C)
{
    __shared__ alignas(16) _Float16 As[128 * 64];
    __shared__ alignas(16) _Float16 Bs[128 * 64];
    const int tid = threadIdx.x;
    const int l   = tid & 63;
    const int w   = tid >> 6;
    const int wm  = w >> 1;
    const int wn  = w & 1;
    const int bm0 = blockIdx.y * 128;
    const int bn0 = blockIdx.x * 128;
    const int fr  = l & 15;
    const int fg  = l >> 4;
    const int srow  = l >> 3;
    const int sslot = l & 7;

#pragma unroll
    for (int i = 0; i < 4; ++i) {
        const int r0   = w * 32 + i * 8;
        const int rowA = r0 + srow;
        const int slot = sslot ^ (rowA & 7);
        __builtin_amdgcn_global_load_lds(
            (const __attribute__((address_space(1))) void*)&A[(size_t)(bm0 + rowA) * 64 + slot * 8],
            (__attribute__((address_space(3))) void*)&As[r0 * 64], 16, 0, 0);
        __builtin_amdgcn_global_load_lds(
            (const __attribute__((address_space(1))) void*)&BT[(size_t)(bn0 + rowA) * 64 + slot * 8],
            (__attribute__((address_space(3))) void*)&Bs[r0 * 64], 16, 0, 0);
    }
    __syncthreads();

    f32x4 acc[4][4] = {};
#pragma unroll
    for (int ks = 0; ks < 2; ++ks) {
        h8_t af[4], bf[4];
#pragma unroll
        for (int mt = 0; mt < 4; ++mt) {
            int row = wm * 64 + mt * 16 + fr;
            int sg  = ks * 4 + fg;
            af[mt] = *reinterpret_cast<const h8_t*>(&As[row * 64 + ((sg ^ (row & 7)) << 3)]);
        }
#pragma unroll
        for (int nt = 0; nt < 4; ++nt) {
            int row = wn * 64 + nt * 16 + fr;
            int sg  = ks * 4 + fg;
            bf[nt] = *reinterpret_cast<const h8_t*>(&Bs[row * 64 + ((sg ^ (row & 7)) << 3)]);
        }
#pragma unroll
        for (int mt = 0; mt < 4; ++mt)
#pragma unroll
            for (int nt = 0; nt < 4; ++nt)
                acc[mt][nt] = __builtin_amdgcn_mfma_f32_16x16x32_f16(af[mt], bf[nt],
                                                                     acc[mt][nt], 0, 0, 0);
    }

#pragma unroll
    for (int nt = 0; nt < 4; ++nt) {
        const int col = bn0 + wn * 64 + nt * 16 + fr;
        const float bv = bias[col];
#pragma unroll
        for (int mt = 0; mt < 4; ++mt)
#pragma unroll
            for (int rg = 0; rg < 4; ++rg) {
                const int row = bm0 + wm * 64 + mt * 16 + fg * 4 + rg;
                float v = acc[mt][nt][rg] + bv;
                C[(size_t)row * 1024 + col] = (_Float16)fmaxf(v, NEG_SLOPE * v);
            }
    }
}

// ---------------------------------------------------------------------------
// K3 v2: h2t = pack(leaky(h1 @ W2 + b2)). BM=64, BN=128, BK=64.
// Grid (8, 64) = 512 WGs (2/CU vs v1's 1/CU). Staging = K2's proven 8-slot
// XOR involution (128B rows). 16 K-iters, 16 MFMA/wave/iter.
// ---------------------------------------------------------------------------
__global__ __launch_bounds__(256) void gemm_mfma_f16_v2(const _Float16* __restrict__ A,
                                                        const _Float16* __restrict__ BT,
                                                        const float* __restrict__ bias,
                                                        _Float16* __restrict__ h2t)
{
    __shared__ alignas(16) _Float16 As[64 * 64];    // 8 KB
    __shared__ alignas(16) _Float16 Bs[128 * 64];   // 16 KB
    const int tid = threadIdx.x;
    const int l   = tid & 63;
    const int w   = tid >> 6;
    const int wm  = w >> 1;            // 2 row-groups of 32
    const int wn  = w & 1;             // 2 col-groups of 64
    const int bm0 = blockIdx.y * 64;
    const int bn0 = blockIdx.x * 128;
    const int fr  = l & 15;
    const int fg  = l >> 4;
    const int srow  = l >> 3;
    const int sslot = l & 7;

    f32x4 acc[2][4] = {};

    for (int k0 = 0; k0 < 1024; k0 += 64) {
#pragma unroll
        for (int i = 0; i < 2; ++i) {          // A: 64 rows, 8-row issues
            const int r0   = w * 16 + i * 8;
            const int rowA = r0 + srow;
            const int slot = sslot ^ (rowA & 7);
            __builtin_amdgcn_global_load_lds(
                (const __attribute__((address_space(1))) void*)&A[(size_t)(bm0 + rowA) * 1024 + k0 + slot * 8],
                (__attribute__((address_space(3))) void*)&As[r0 * 64], 16, 0, 0);
        }
#pragma unroll
        for (int i = 0; i < 4; ++i) {          // B: 128 rows
            const int r0   = w * 32 + i * 8;
            const int rowB = r0 + srow;
            const int slot = sslot ^ (rowB & 7);
            __builtin_amdgcn_global_load_lds(
                (const __attribute__((address_space(1))) void*)&BT[(size_t)(bn0 + rowB) * 1024 + k0 + slot * 8],
                (__attribute__((address_space(3))) void*)&Bs[r0 * 64], 16, 0, 0);
        }
        __syncthreads();

#pragma unroll
        for (int ks = 0; ks < 2; ++ks) {
            h8_t af[2], bf[4];
#pragma unroll
            for (int mt = 0; mt < 2; ++mt) {
                int row = wm * 32 + mt * 16 + fr;
                int sg  = ks * 4 + fg;
                af[mt] = *reinterpret_cast<const h8_t*>(&As[row * 64 + ((sg ^ (row & 7)) << 3)]);
            }
#pragma unroll
            for (int nt = 0; nt < 4; ++nt) {
                int row = wn * 64 + nt * 16 + fr;
                int sg  = ks * 4 + fg;
                bf[nt] = *reinterpret_cast<const h8_t*>(&Bs[row * 64 + ((sg ^ (row & 7)) << 3)]);
            }
#pragma unroll
            for (int mt = 0; mt < 2; ++mt)
#pragma unroll
                for (int nt = 0; nt < 4; ++nt)
                    acc[mt][nt] = __builtin_amdgcn_mfma_f32_16x16x32_f16(af[mt], bf[nt],
                                                                         acc[mt][nt], 0, 0, 0);
        }
        __syncthreads();
    }

    const int rblk0 = (bm0 >> 4) + wm * 2;
    const int cblk0 = (bn0 >> 4) + wn * 4;
#pragma unroll
    for (int nt = 0; nt < 4; ++nt) {
        const int col = bn0 + wn * 64 + nt * 16 + fr;
        const float bv = bias[col];
#pragma unroll
        for (int mt = 0; mt < 2; ++mt) {
            h4_t pk;
#pragma unroll
            for (int r = 0; r < 4; ++r) {
                float v = acc[mt][nt][r] + bv;
                pk[r] = (_Float16)fmaxf(v, NEG_SLOPE * v);
            }
            *reinterpret_cast<h4_t*>(
                &h2t[(((size_t)(cblk0 + nt) * 256 + rblk0 + mt) * 16 + fr) * 16 + fg * 4]) = pk;
        }
    }
}

// ---------------------------------------------------------------------------
// K4: fused additive chain v5 — 2 independent row-tiles per wave.
// WG covers 128 rows; grid (32, 16) = 512 WGs; LDS 60KB -> 2 WG/CU.
// Sync structure identical to v4 (lgkm0 placement, 1 barrier per r).
// Stage: 22 chans x 1KB: [0,4): h (8 rblks), [4,22): wpack frags.
// ---------------------------------------------------------------------------
#define RCH 4

__global__ __launch_bounds__(256) void fused_tail5(const _Float16* __restrict__ h2t,
                                                   const _Float16* __restrict__ wpack,
                                                   const float* __restrict__ a1b,
                                                   const float* __restrict__ a1bias,
                                                   const float* __restrict__ a2b,
                                                   const float* __restrict__ a2bias,
                                                   float* __restrict__ partials)
{
    __shared__ alignas(16) _Float16 stage[2][11264];  // 2 x 22KB
    __shared__ alignas(16) _Float16 act[4][2048];     // per-wave, 2 tiles (16KB)

    const int tid = threadIdx.x;
    const int l = tid & 63, w = tid >> 6;
    const int c = l & 15, q = l >> 4;
    const int row0  = blockIdx.x * 128;
    const int rbase = blockIdx.y * RCH;
    const float b1s = a1bias[0], b2s = a2bias[0];

    const unsigned trl   = l * 8;
    const unsigned abase = lds_off(&act[w][0]);

    float b1v[RCH][4], b2v[RCH][4];
#pragma unroll
    for (int rl = 0; rl < RCH; ++rl)
#pragma unroll
        for (int nt = 0; nt < 4; ++nt) {
            b1v[rl][nt] = a1b[(rbase + rl) * 64 + nt * 16 + c] + b1s;
            b2v[rl][nt] = a2b[(rbase + rl) * 64 + nt * 16 + c] + b2s;
        }

    auto STAGE = [&](int rl, int b) {
        const int r = rbase + rl;
        const _Float16* hsrc = h2t + ((size_t)r * 256 + blockIdx.x * 8) * 256;
        const _Float16* wsrc = wpack + (size_t)r * 9216;
#pragma unroll
        for (int i = 0; i < 6; ++i) {
            const int ch = i * 4 + w;
            if (ch < 22) {
                const _Float16* src = (ch < 4) ? (hsrc + ch * 512) : (wsrc + (ch - 4) * 512);
                __builtin_amdgcn_global_load_lds(
                    (const __attribute__((address_space(1))) void*)(src + l * 8),
                    (__attribute__((address_space(3))) void*)&stage[b][ch * 512], 16, 0, 0);
            }
        }
    };

    STAGE(0, 0);
    __syncthreads();

    f32x4 accT[2][4] = {};
    int cur = 0;

#pragma unroll
    for (int rl = 0; rl < RCH; ++rl) {
        if (rl + 1 < RCH) STAGE(rl + 1, cur ^ 1);

        const _Float16* sp = &stage[cur][0];
        const unsigned sbytes = lds_off(sp);

        // ---- phase A: a[j] = leaky(h_tile[j] @ W1r + bias)   (tiles j=0,1 -> rblk w, w+4)
        h4_t ha0 = tr16(sbytes + (unsigned)(w) * 512 + trl);
        h4_t ha1 = tr16(sbytes + (unsigned)(w + 4) * 512 + trl);
        lgkm0();
        f32x4 pa[2][4];
#pragma unroll
        for (int nt = 0; nt < 4; ++nt) {
            h4_t bf = *reinterpret_cast<const h4_t*>(&sp[2048 + nt * 256 + l * 4]);
            pa[0][nt] = __builtin_amdgcn_mfma_f32_16x16x16f16(ha0, bf, (f32x4){0.f,0.f,0.f,0.f}, 0, 0, 0);
            pa[1][nt] = __builtin_amdgcn_mfma_f32_16x16x16f16(ha1, bf, (f32x4){0.f,0.f,0.f,0.f}, 0, 0, 0);
        }
#pragma unroll
        for (int j = 0; j < 2; ++j)
#pragma unroll
            for (int nt = 0; nt < 4; ++nt) {
                h4_t pk;
#pragma unroll
                for (int rg = 0; rg < 4; ++rg) {
                    float v = pa[j][nt][rg] + b1v[rl][nt];
                    pk[rg] = (_Float16)fmaxf(v, NEG_SLOPE * v);
                }
                const int kk = nt * 16 + c;
                const int hh = (kk >> 2) & 1;
                const int kp = (kk & 3) | ((kk >> 3) << 2);
                *reinterpret_cast<h4_t*>(&act[w][j * 1024 + hh * 512 + kp * 16 + q * 4]) = pk;
            }
        lgkm0();

        // ---- phase B: a2[j] = leaky(a[j] @ W2r + bias)
        h8_t afB[2][2];
#pragma unroll
        for (int j = 0; j < 2; ++j)
#pragma unroll
            for (int kt = 0; kt < 2; ++kt) {
                h4_t lo = tr16(abase + (unsigned)(j * 2048 + kt * 512) + trl);
                h4_t hi = tr16(abase + (unsigned)(j * 2048 + 1024 + kt * 512) + trl);
                afB[j][kt] = __builtin_shufflevector(lo, hi, 0, 1, 2, 3, 4, 5, 6, 7);
            }
        lgkm0();
        f32x4 pb[2][4] = {};
#pragma unroll
        for (int kt = 0; kt < 2; ++kt)
#pragma unroll
            for (int nt = 0; nt < 4; ++nt) {
                h8_t bf = *reinterpret_cast<const h8_t*>(&sp[3072 + kt * 2048 + nt * 512 + l * 8]);
                pb[0][nt] = __builtin_amdgcn_mfma_f32_16x16x32_f16(afB[0][kt], bf, pb[0][nt], 0, 0, 0);
                pb[1][nt] = __builtin_amdgcn_mfma_f32_16x16x32_f16(afB[1][kt], bf, pb[1][nt], 0, 0, 0);
            }
#pragma unroll
        for (int j = 0; j < 2; ++j)
#pragma unroll
            for (int nt = 0; nt < 4; ++nt) {
                h4_t pk;
#pragma unroll
                for (int rg = 0; rg < 4; ++rg) {
                    float v = pb[j][nt][rg] + b2v[rl][nt];
                    pk[rg] = (_Float16)fmaxf(v, NEG_SLOPE * v);
                }
                const int kk = nt * 16 + c;
                const int hh = (kk >> 2) & 1;
                const int kp = (kk & 3) | ((kk >> 3) << 2);
                *reinterpret_cast<h4_t*>(&act[w][j * 1024 + hh * 512 + kp * 16 + q * 4]) = pk;
            }
        lgkm0();

        // ---- phase C: t2[j] += a2[j] @ WpR
        h8_t afC[2][2];
#pragma unroll
        for (int j = 0; j < 2; ++j)
#pragma unroll
            for (int kt = 0; kt < 2; ++kt) {
                h4_t lo = tr16(abase + (unsigned)(j * 2048 + kt * 512) + trl);
                h4_t hi = tr16(abase + (unsigned)(j * 2048 + 1024 + kt * 512) + trl);
                afC[j][kt] = __builtin_shufflevector(lo, hi, 0, 1, 2, 3, 4, 5, 6, 7);
            }
        lgkm0();
#pragma unroll
        for (int kt = 0; kt < 2; ++kt)
#pragma unroll
            for (int nt = 0; nt < 4; ++nt) {
                h8_t bf = *reinterpret_cast<const h8_t*>(&sp[7168 + kt * 2048 + nt * 512 + l * 8]);
                accT[0][nt] = __builtin_amdgcn_mfma_f32_16x16x32_f16(afC[0][kt], bf, accT[0][nt], 0, 0, 0);
                accT[1][nt] = __builtin_amdgcn_mfma_f32_16x16x32_f16(afC[1][kt], bf, accT[1][nt], 0, 0, 0);
            }

        __syncthreads();   // drains vmcnt for next stage + frees stage[cur]
        cur ^= 1;
    }

#pragma unroll
    for (int j = 0; j < 2; ++j)
#pragma unroll
        for (int nt = 0; nt < 4; ++nt)
#pragma unroll
            for (int rg = 0; rg < 4; ++rg)
                partials[((size_t)blockIdx.y * 4096 + row0 + (w + 4 * j) * 16 + q * 4 + rg) * 64
                         + nt * 16 + c] = accT[j][nt][rg];
}

// ---------------------------------------------------------------------------
// K5: reduce 16 partials + bp2, dot with Wl, add bl -> out[4096]
// ---------------------------------------------------------------------------
__global__ __launch_bounds__(256) void reduce_out(const float* __restrict__ partials,
                                                  const float* __restrict__ bp2,
                                                  const float* __restrict__ Wl,
                                                  const float* __restrict__ bl,
                                                  float* __restrict__ out)
{
    const int tid = threadIdx.x;
    const int row = blockIdx.x * 4 + (tid >> 6);
    const int col = tid & 63;
    float s = bp2[col];
#pragma unroll
    for (int c = 0; c < 16; ++c)
        s += partials[(size_t)c * 262144 + (size_t)row * 64 + col];
    s *= Wl[col];
    s += __shfl_xor(s, 1);
    s += __shfl_xor(s, 2);
    s += __shfl_xor(s, 4);
    s += __shfl_xor(s, 8);
    s += __shfl_xor(s, 16);
    s += __shfl_xor(s, 32);
    if (col == 0) out[row] = s + bl[0];
}

// ---------------------------------------------------------------------------
extern "C" void kernel_launch(void* const* d_in, const int* in_sizes, int n_in,
                              void* d_out, int out_size, void* d_ws, size_t ws_size,
                              hipStream_t stream)
{
    const float* x      = (const float*)d_in[0];
    const float* Wpca   = (const float*)d_in[1];
    const float* bpca   = (const float*)d_in[2];
    const float* W1     = (const float*)d_in[3];
    const float* b1     = (const float*)d_in[4];
    const float* W2     = (const float*)d_in[5];
    const float* b2     = (const float*)d_in[6];
    const float* a1W    = (const float*)d_in[7];
    const float* a1b    = (const float*)d_in[8];
    const float* a1bias = (const float*)d_in[9];
    const float* a2W    = (const float*)d_in[10];
    const float* a2b    = (const float*)d_in[11];
    const float* a2bias = (const float*)d_in[12];
    const float* Wp2    = (const float*)d_in[13];
    const float* bp2    = (const float*)d_in[14];
    const float* Wl     = (const float*)d_in[15];
    const float* bl     = (const float*)d_in[16];
    float* out = (float*)d_out;

    // workspace layout (bytes) — verified non-overlapping:
    //   t16 [0,0.5M)  h1h [1M,9M)  h2t [9M,17M)  W2T [17M,19M)
    //   wpack [19M,20.13M)  W1T [21M,21.13M)  partials [22M,38.8M)
    char* wsb = (char*)d_ws;
    _Float16* t16      = (_Float16*)(wsb);
    _Float16* h1h      = (_Float16*)(wsb + (1ull  << 20));
    _Float16* h2t      = (_Float16*)(wsb + (9ull  << 20));
    _Float16* W2T      = (_Float16*)(wsb + (17ull << 20));
    _Float16* wpack    = (_Float16*)(wsb + (19ull << 20));
    _Float16* W1T      = (_Float16*)(wsb + (21ull << 20));
    float*    partials = (float*)   (wsb + (22ull << 20));
    float*    tpart    = (float*)   (wsb + (9ull  << 20));   // aliases h2t (dead then)

    // prep: W2T + W1T + wpack in one launch
    prep_weights<<<dim3(3392), 256, 0, stream>>>(W2, W1, a1W, a2W, Wp2, W2T, W1T, wpack);
    // t = x @ W_pca + b_pca  (split-K fp32, combine -> fp16)
    gemm_n64_splitk<<<dim3(128, 8), 256, 0, stream>>>(x, Wpca, tpart);
    combine_t16<<<dim3(1024), 256, 0, stream>>>(tpart, bpca, t16);
    // h1 = leaky(t @ W1 + b1) via MFMA (K=64) -> linear fp16
    gemm_k64_mfma<<<dim3(8, 32), 256, 0, stream>>>(t16, W1T, b1, h1h);
    // h2 (packed) = leaky(h1 @ W2 + b2) via MFMA  (v2: BM=64/BK=64, 512 WGs)
    gemm_mfma_f16_v2<<<dim3(8, 64), 256, 0, stream>>>(h1h, W2T, b2, h2t);
    // fused additive chain (MFMA, 2 tiles/wave) -> partial t2 per r-chunk
    fused_tail5<<<dim3(32, 16), 256, 0, stream>>>(h2t, wpack, a1b, a1bias,
                                                  a2b, a2bias, partials);
    // reduce partials + PCA2 bias + last layer
    reduce_out<<<dim3(1024), 256, 0, stream>>>(partials, bp2, Wl, bl, out);
}